// Round 1
// baseline (3726.698 us; speedup 1.0000x reference)
//
#include <hip/hip_runtime.h>
#include <math.h>

#define N_NODES 50000
#define N_EDGES 800000
#define ET (N_EDGES + N_NODES)   /* 850000 edges incl. self-loops */
#define F_IN 512
#define HID 64
#define HEADS 4
#define C1 (HEADS * HID)         /* 256 */
#define NCLS 40
#define NEG_SLOPE 0.2f

__device__ __forceinline__ float leaky(float x) { return x >= 0.f ? x : NEG_SLOPE * x; }

__device__ __forceinline__ void edge_sd(int e, const int* __restrict__ ei,
                                        const float* __restrict__ ew,
                                        int& s, int& d, float& w) {
    if (e < N_EDGES) { s = ei[e]; d = ei[N_EDGES + e]; w = ew[e]; }
    else             { s = d = e - N_EDGES; w = 1.f; }
}

// ---------------- GEMM1: X[50000,512] @ W1[512,256] -> H1[50000,256] ----------------
__global__ __launch_bounds__(256) void gemm1_kernel(const float* __restrict__ X,
                                                    const float* __restrict__ W,
                                                    float* __restrict__ H) {
    __shared__ float As[64][17];
    __shared__ float Bs[16][68];
    const int tid = threadIdx.y * 16 + threadIdx.x;   // block 16x16
    const int m0 = blockIdx.y * 64;
    const int n0 = blockIdx.x * 64;
    float acc[4][4] = {};
    for (int k0 = 0; k0 < F_IN; k0 += 16) {
        #pragma unroll
        for (int i = 0; i < 4; i++) {                 // A tile 64x16
            int idx = tid + i * 256;
            int r = idx >> 4, c = idx & 15;
            int gr = m0 + r;
            As[r][c] = (gr < N_NODES) ? X[(size_t)gr * F_IN + k0 + c] : 0.f;
        }
        #pragma unroll
        for (int i = 0; i < 4; i++) {                 // B tile 16x64
            int idx = tid + i * 256;
            int r = idx >> 6, c = idx & 63;
            Bs[r][c] = W[(k0 + r) * C1 + n0 + c];
        }
        __syncthreads();
        #pragma unroll
        for (int kk = 0; kk < 16; kk++) {
            float a[4], b[4];
            #pragma unroll
            for (int i = 0; i < 4; i++) a[i] = As[threadIdx.y * 4 + i][kk];
            #pragma unroll
            for (int j = 0; j < 4; j++) b[j] = Bs[kk][threadIdx.x * 4 + j];
            #pragma unroll
            for (int i = 0; i < 4; i++)
                #pragma unroll
                for (int j = 0; j < 4; j++) acc[i][j] += a[i] * b[j];
        }
        __syncthreads();
    }
    #pragma unroll
    for (int i = 0; i < 4; i++) {
        int gr = m0 + threadIdx.y * 4 + i;
        if (gr < N_NODES) {
            #pragma unroll
            for (int j = 0; j < 4; j++)
                H[(size_t)gr * C1 + n0 + threadIdx.x * 4 + j] = acc[i][j];
        }
    }
}

// -------- per-(node,head) attention logits: AS[n,h]=h·a_src, AD[n,h]=h·a_dst --------
__global__ void alphas1_kernel(const float* __restrict__ H, const float* __restrict__ a_src,
                               const float* __restrict__ a_dst, float* __restrict__ AS,
                               float* __restrict__ AD) {
    int t = blockIdx.x * blockDim.x + threadIdx.x;
    if (t >= N_NODES * HEADS) return;
    int n = t >> 2, h = t & 3;
    const float* hp = H + (size_t)n * C1 + h * HID;
    const float* sp = a_src + h * HID;
    const float* dp = a_dst + h * HID;
    float s = 0.f, d = 0.f;
    #pragma unroll 16
    for (int k = 0; k < HID; k++) { float v = hp[k]; s += v * sp[k]; d += v * dp[k]; }
    AS[t] = s; AD[t] = d;
}

// ---- denom pass (no max-shift needed: |logits| < ~4, exp can't overflow) ----
__global__ void denom1_kernel(const int* __restrict__ ei, const float* __restrict__ ew,
                              const float* __restrict__ AS, const float* __restrict__ AD,
                              float* __restrict__ DEN) {
    int e = blockIdx.x * blockDim.x + threadIdx.x;
    if (e >= ET) return;
    int s, d; float w;
    edge_sd(e, ei, ew, s, d, w);
    #pragma unroll
    for (int h = 0; h < HEADS; h++) {
        float p = expf(leaky(AS[s * 4 + h] + AD[d * 4 + h]));
        atomicAdd(&DEN[d * 4 + h], p);
    }
}

// ---- aggregation: wave-per-edge, each thread 4 channels (float4 gather + atomics) ----
__global__ __launch_bounds__(256) void agg1_kernel(const int* __restrict__ ei,
                                                   const float* __restrict__ ew,
                                                   const float* __restrict__ AS,
                                                   const float* __restrict__ AD,
                                                   const float* __restrict__ DEN,
                                                   const float* __restrict__ H,
                                                   float* __restrict__ OUT) {
    int t = blockIdx.x * 256 + threadIdx.x;    // ET*64 = 54.4M < 2^31
    if (t >= ET * 64) return;
    int e = t >> 6, lane = t & 63;
    int s, d; float w;
    edge_sd(e, ei, ew, s, d, w);
    int h = lane >> 4;                          // 16 lanes (64 ch) per head
    float alpha = expf(leaky(AS[s * 4 + h] + AD[d * 4 + h])) * w / (DEN[d * 4 + h] + 1e-16f);
    const float4 hv = *(const float4*)(H + (size_t)s * C1 + lane * 4);
    float* op = OUT + (size_t)d * C1 + lane * 4;
    atomicAdd(op + 0, hv.x * alpha);
    atomicAdd(op + 1, hv.y * alpha);
    atomicAdd(op + 2, hv.z * alpha);
    atomicAdd(op + 3, hv.w * alpha);
}

__global__ void bias_relu_kernel(float* __restrict__ O, const float* __restrict__ b) {
    int t = blockIdx.x * blockDim.x + threadIdx.x;
    if (t >= N_NODES * C1) return;
    float v = O[t] + b[t & (C1 - 1)];
    O[t] = v > 0.f ? v : 0.f;
}

// ---------------- GEMM2: H[50000,256] @ W2[256,40] -> H2[50000,40] ----------------
__global__ __launch_bounds__(256) void gemm2_kernel(const float* __restrict__ H,
                                                    const float* __restrict__ W2,
                                                    float* __restrict__ H2) {
    __shared__ float Ws[C1 * NCLS];             // 40 KB
    for (int i = threadIdx.x; i < C1 * NCLS; i += 256) Ws[i] = W2[i];
    __syncthreads();
    int wave = threadIdx.x >> 6, lane = threadIdx.x & 63;
    int n = blockIdx.x * 4 + wave;              // one wave per node
    if (n >= N_NODES || lane >= NCLS) return;
    const float* hp = H + (size_t)n * C1;
    float acc = 0.f;
    for (int k = 0; k < C1; k += 4) {
        float4 hv = *(const float4*)(hp + k);
        acc += hv.x * Ws[(k + 0) * NCLS + lane] + hv.y * Ws[(k + 1) * NCLS + lane]
             + hv.z * Ws[(k + 2) * NCLS + lane] + hv.w * Ws[(k + 3) * NCLS + lane];
    }
    H2[(size_t)n * NCLS + lane] = acc;
}

__global__ void alphas2_kernel(const float* __restrict__ H2, const float* __restrict__ a_src,
                               const float* __restrict__ a_dst, float* __restrict__ AS,
                               float* __restrict__ AD) {
    int n = blockIdx.x * blockDim.x + threadIdx.x;
    if (n >= N_NODES) return;
    float s = 0.f, d = 0.f;
    #pragma unroll
    for (int k = 0; k < NCLS; k++) {
        float v = H2[(size_t)n * NCLS + k];
        s += v * a_src[k]; d += v * a_dst[k];
    }
    AS[n] = s; AD[n] = d;
}

__global__ void denom2_kernel(const int* __restrict__ ei, const float* __restrict__ ew,
                              const float* __restrict__ AS, const float* __restrict__ AD,
                              float* __restrict__ DEN) {
    int e = blockIdx.x * blockDim.x + threadIdx.x;
    if (e >= ET) return;
    int s, d; float w;
    edge_sd(e, ei, ew, s, d, w);
    atomicAdd(&DEN[d], expf(leaky(AS[s] + AD[d])));
}

__global__ void out_init_kernel(float* __restrict__ O, const float* __restrict__ b2) {
    int t = blockIdx.x * blockDim.x + threadIdx.x;
    if (t >= N_NODES * NCLS) return;
    O[t] = b2[t % NCLS];
}

__global__ void agg2_kernel(const int* __restrict__ ei, const float* __restrict__ ew,
                            const float* __restrict__ AS, const float* __restrict__ AD,
                            const float* __restrict__ DEN, const float* __restrict__ H2,
                            float* __restrict__ OUT) {
    int t = blockIdx.x * blockDim.x + threadIdx.x;   // ET*40 = 34M
    if (t >= ET * NCLS) return;
    int e = t / NCLS, c = t - e * NCLS;
    int s, d; float w;
    edge_sd(e, ei, ew, s, d, w);
    float alpha = expf(leaky(AS[s] + AD[d])) * w / (DEN[d] + 1e-16f);
    atomicAdd(OUT + (size_t)d * NCLS + c, H2[(size_t)s * NCLS + c] * alpha);
}

extern "C" void kernel_launch(void* const* d_in, const int* in_sizes, int n_in,
                              void* d_out, int out_size, void* d_ws, size_t ws_size,
                              hipStream_t stream) {
    const float* x   = (const float*)d_in[0];
    const int*   ei  = (const int*)d_in[1];
    const float* ew  = (const float*)d_in[2];
    const float* W1  = (const float*)d_in[3];
    const float* a_s1 = (const float*)d_in[4];
    const float* a_d1 = (const float*)d_in[5];
    const float* b1  = (const float*)d_in[6];
    const float* W2  = (const float*)d_in[7];
    const float* a_s2 = (const float*)d_in[8];
    const float* a_d2 = (const float*)d_in[9];
    const float* b2  = (const float*)d_in[10];
    float* out = (float*)d_out;

    // workspace layout (f32): H1[N,256] OUT1[N,256] AS1[N,4] AD1[N,4] DEN1[N,4]
    //                         H2[N,40] AS2[N] AD2[N] DEN2[N]   -> 113.4 MB total
    float* H1   = (float*)d_ws;
    float* OUT1 = H1 + (size_t)N_NODES * C1;
    float* AS1  = OUT1 + (size_t)N_NODES * C1;
    float* AD1  = AS1 + N_NODES * HEADS;
    float* DEN1 = AD1 + N_NODES * HEADS;
    float* H2   = DEN1 + N_NODES * HEADS;
    float* AS2  = H2 + (size_t)N_NODES * NCLS;
    float* AD2  = AS2 + N_NODES;
    float* DEN2 = AD2 + N_NODES;

    // zero everything from OUT1 onward (covers OUT1, DEN1, DEN2 accumulators)
    size_t zero_bytes = (size_t)N_NODES * (C1 + 3 * HEADS + NCLS + 3) * sizeof(float);
    hipMemsetAsync(OUT1, 0, zero_bytes, stream);

    // ---------------- layer 1 ----------------
    gemm1_kernel<<<dim3(C1 / 64, (N_NODES + 63) / 64), dim3(16, 16), 0, stream>>>(x, W1, H1);
    alphas1_kernel<<<(N_NODES * HEADS + 255) / 256, 256, 0, stream>>>(H1, a_s1, a_d1, AS1, AD1);
    denom1_kernel<<<(ET + 255) / 256, 256, 0, stream>>>(ei, ew, AS1, AD1, DEN1);
    agg1_kernel<<<(ET * 64) / 256, 256, 0, stream>>>(ei, ew, AS1, AD1, DEN1, H1, OUT1);
    bias_relu_kernel<<<(N_NODES * C1) / 256, 256, 0, stream>>>(OUT1, b1);

    // ---------------- layer 2 ----------------
    gemm2_kernel<<<(N_NODES + 3) / 4, 256, 0, stream>>>(OUT1, W2, H2);
    alphas2_kernel<<<(N_NODES + 255) / 256, 256, 0, stream>>>(H2, a_s2, a_d2, AS2, AD2);
    denom2_kernel<<<(ET + 255) / 256, 256, 0, stream>>>(ei, ew, AS2, AD2, DEN2);
    out_init_kernel<<<(N_NODES * NCLS + 255) / 256, 256, 0, stream>>>(out, b2);
    agg2_kernel<<<(ET * NCLS + 255) / 256, 256, 0, stream>>>(ei, ew, AS2, AD2, DEN2, H2, out);
}

// Round 2
// 904.693 us; speedup vs baseline: 4.1193x; 4.1193x over previous
//
#include <hip/hip_runtime.h>
#include <math.h>

#define N_NODES 50000
#define N_EDGES 800000
#define ET (N_EDGES + N_NODES)   /* 850000 edges incl. self-loops */
#define F_IN 512
#define HID 64
#define HEADS 4
#define C1 (HEADS * HID)         /* 256 */
#define NCLS 40
#define NEG_SLOPE 0.2f
#define NCHUNK ((N_NODES + 255) / 256)   /* 196 */

__device__ __forceinline__ float leaky(float x) { return x >= 0.f ? x : NEG_SLOPE * x; }

__device__ __forceinline__ void edge_sd(int e, const int* __restrict__ ei,
                                        const float* __restrict__ ew,
                                        int& s, int& d, float& w) {
    if (e < N_EDGES) { s = ei[e]; d = ei[N_EDGES + e]; w = ew[e]; }
    else             { s = d = e - N_EDGES; w = 1.f; }
}

// ======================= CSR construction (per call) =======================
__global__ void hist_kernel(const int* __restrict__ ei, int* __restrict__ cnt) {
    int e = blockIdx.x * blockDim.x + threadIdx.x;
    if (e >= ET) return;
    int d = (e < N_EDGES) ? ei[N_EDGES + e] : e - N_EDGES;
    atomicAdd(&cnt[d], 1);
}

__global__ void chunk_sum_kernel(const int* __restrict__ cnt, int* __restrict__ sums) {
    __shared__ int sm[256];
    int i = blockIdx.x * 256 + threadIdx.x;
    sm[threadIdx.x] = (i < N_NODES) ? cnt[i] : 0;
    __syncthreads();
    for (int s = 128; s > 0; s >>= 1) {
        if (threadIdx.x < s) sm[threadIdx.x] += sm[threadIdx.x + s];
        __syncthreads();
    }
    if (threadIdx.x == 0) sums[blockIdx.x] = sm[0];
}

__global__ void scan_sums_kernel(int* __restrict__ sums) {
    if (threadIdx.x == 0) {
        int acc = 0;
        for (int i = 0; i < NCHUNK; i++) { int v = sums[i]; sums[i] = acc; acc += v; }
    }
}

__global__ void rowptr_kernel(const int* __restrict__ cnt, const int* __restrict__ sums,
                              int* __restrict__ row_ptr, int* __restrict__ fill) {
    __shared__ int sm[256];
    int i = blockIdx.x * 256 + threadIdx.x;
    int v = (i < N_NODES) ? cnt[i] : 0;
    sm[threadIdx.x] = v;
    __syncthreads();
    #pragma unroll
    for (int s = 1; s < 256; s <<= 1) {
        int t = (threadIdx.x >= s) ? sm[threadIdx.x - s] : 0;
        __syncthreads();
        sm[threadIdx.x] += t;
        __syncthreads();
    }
    int excl = sm[threadIdx.x] - v + sums[blockIdx.x];
    if (i < N_NODES) { row_ptr[i] = excl; fill[i] = excl; }
}

__global__ void scatter_kernel(const int* __restrict__ ei, const float* __restrict__ ew,
                               int* __restrict__ fill, int* __restrict__ esrc,
                               float* __restrict__ ewf) {
    int e = blockIdx.x * blockDim.x + threadIdx.x;
    if (e >= ET) return;
    int s, d; float w;
    edge_sd(e, ei, ew, s, d, w);
    int pos = atomicAdd(&fill[d], 1);
    esrc[pos] = s; ewf[pos] = w;
}

// ---------------- GEMM1: X[50000,512] @ W1[512,256] -> H1[50000,256] ----------------
__global__ __launch_bounds__(256) void gemm1_kernel(const float* __restrict__ X,
                                                    const float* __restrict__ W,
                                                    float* __restrict__ H) {
    __shared__ float As[64][17];
    __shared__ float Bs[16][68];
    const int tid = threadIdx.y * 16 + threadIdx.x;
    const int m0 = blockIdx.y * 64;
    const int n0 = blockIdx.x * 64;
    float acc[4][4] = {};
    for (int k0 = 0; k0 < F_IN; k0 += 16) {
        #pragma unroll
        for (int i = 0; i < 4; i++) {
            int idx = tid + i * 256;
            int r = idx >> 4, c = idx & 15;
            int gr = m0 + r;
            As[r][c] = (gr < N_NODES) ? X[(size_t)gr * F_IN + k0 + c] : 0.f;
        }
        #pragma unroll
        for (int i = 0; i < 4; i++) {
            int idx = tid + i * 256;
            int r = idx >> 6, c = idx & 63;
            Bs[r][c] = W[(k0 + r) * C1 + n0 + c];
        }
        __syncthreads();
        #pragma unroll
        for (int kk = 0; kk < 16; kk++) {
            float a[4], b[4];
            #pragma unroll
            for (int i = 0; i < 4; i++) a[i] = As[threadIdx.y * 4 + i][kk];
            #pragma unroll
            for (int j = 0; j < 4; j++) b[j] = Bs[kk][threadIdx.x * 4 + j];
            #pragma unroll
            for (int i = 0; i < 4; i++)
                #pragma unroll
                for (int j = 0; j < 4; j++) acc[i][j] += a[i] * b[j];
        }
        __syncthreads();
    }
    #pragma unroll
    for (int i = 0; i < 4; i++) {
        int gr = m0 + threadIdx.y * 4 + i;
        if (gr < N_NODES) {
            #pragma unroll
            for (int j = 0; j < 4; j++)
                H[(size_t)gr * C1 + n0 + threadIdx.x * 4 + j] = acc[i][j];
        }
    }
}

// -------- per-(node,head) attention logits --------
__global__ void alphas1_kernel(const float* __restrict__ H, const float* __restrict__ a_src,
                               const float* __restrict__ a_dst, float* __restrict__ AS,
                               float* __restrict__ AD) {
    int t = blockIdx.x * blockDim.x + threadIdx.x;
    if (t >= N_NODES * HEADS) return;
    int n = t >> 2, h = t & 3;
    const float* hp = H + (size_t)n * C1 + h * HID;
    const float* sp = a_src + h * HID;
    const float* dp = a_dst + h * HID;
    float s = 0.f, d = 0.f;
    #pragma unroll 16
    for (int k = 0; k < HID; k++) { float v = hp[k]; s += v * sp[k]; d += v * dp[k]; }
    AS[t] = s; AD[t] = d;
}

// ---- fused CSR aggregation layer1: denom + weighted sum + bias + ReLU, no atomics ----
__global__ __launch_bounds__(256) void agg1_csr_kernel(const int* __restrict__ row_ptr,
                                                       const int* __restrict__ esrc,
                                                       const float* __restrict__ ewf,
                                                       const float* __restrict__ AS,
                                                       const float* __restrict__ AD,
                                                       const float* __restrict__ H,
                                                       const float* __restrict__ b1,
                                                       float* __restrict__ OUT) {
    int n = blockIdx.x;                 // one block per dst node
    int c = threadIdx.x;                // channel 0..255
    int h = c >> 6;                     // head
    int beg = row_ptr[n];
    int end = (n + 1 < N_NODES) ? row_ptr[n + 1] : ET;
    float ad = AD[n * 4 + h];
    float den = 0.f, acc = 0.f;
    for (int p = beg; p < end; p++) {
        int s = esrc[p];
        float w = ewf[p];
        float pe = __expf(leaky(AS[s * 4 + h] + ad));
        den += pe;
        acc += pe * w * H[(size_t)s * C1 + c];
    }
    float v = acc / (den + 1e-16f) + b1[c];
    OUT[(size_t)n * C1 + c] = v > 0.f ? v : 0.f;
}

// ---------------- GEMM2: H[50000,256] @ W2[256,40] -> H2[50000,40] ----------------
__global__ __launch_bounds__(256) void gemm2_kernel(const float* __restrict__ H,
                                                    const float* __restrict__ W2,
                                                    float* __restrict__ H2) {
    __shared__ float Ws[C1 * NCLS];
    for (int i = threadIdx.x; i < C1 * NCLS; i += 256) Ws[i] = W2[i];
    __syncthreads();
    int wave = threadIdx.x >> 6, lane = threadIdx.x & 63;
    int n = blockIdx.x * 4 + wave;
    if (n >= N_NODES || lane >= NCLS) return;
    const float* hp = H + (size_t)n * C1;
    float acc = 0.f;
    for (int k = 0; k < C1; k += 4) {
        float4 hv = *(const float4*)(hp + k);
        acc += hv.x * Ws[(k + 0) * NCLS + lane] + hv.y * Ws[(k + 1) * NCLS + lane]
             + hv.z * Ws[(k + 2) * NCLS + lane] + hv.w * Ws[(k + 3) * NCLS + lane];
    }
    H2[(size_t)n * NCLS + lane] = acc;
}

__global__ void alphas2_kernel(const float* __restrict__ H2, const float* __restrict__ a_src,
                               const float* __restrict__ a_dst, float* __restrict__ AS,
                               float* __restrict__ AD) {
    int n = blockIdx.x * blockDim.x + threadIdx.x;
    if (n >= N_NODES) return;
    float s = 0.f, d = 0.f;
    #pragma unroll
    for (int k = 0; k < NCLS; k++) {
        float v = H2[(size_t)n * NCLS + k];
        s += v * a_src[k]; d += v * a_dst[k];
    }
    AS[n] = s; AD[n] = d;
}

// ---- fused CSR aggregation layer2: denom + weighted sum + bias, writes d_out ----
__global__ __launch_bounds__(256) void agg2_csr_kernel(const int* __restrict__ row_ptr,
                                                       const int* __restrict__ esrc,
                                                       const float* __restrict__ ewf,
                                                       const float* __restrict__ AS,
                                                       const float* __restrict__ AD,
                                                       const float* __restrict__ H2,
                                                       const float* __restrict__ b2,
                                                       float* __restrict__ OUT) {
    int lane = threadIdx.x & 63;
    int n = blockIdx.x * 4 + (threadIdx.x >> 6);   // one wave per dst node
    if (n >= N_NODES) return;
    int beg = row_ptr[n];
    int end = (n + 1 < N_NODES) ? row_ptr[n + 1] : ET;
    float ad = AD[n];
    float den = 0.f, acc = 0.f;
    for (int p = beg; p < end; p++) {
        int s = esrc[p];
        float w = ewf[p];
        float pe = __expf(leaky(AS[s] + ad));
        den += pe;
        if (lane < NCLS) acc += pe * w * H2[(size_t)s * NCLS + lane];
    }
    if (lane < NCLS)
        OUT[(size_t)n * NCLS + lane] = acc / (den + 1e-16f) + b2[lane];
}

extern "C" void kernel_launch(void* const* d_in, const int* in_sizes, int n_in,
                              void* d_out, int out_size, void* d_ws, size_t ws_size,
                              hipStream_t stream) {
    const float* x    = (const float*)d_in[0];
    const int*   ei   = (const int*)d_in[1];
    const float* ew   = (const float*)d_in[2];
    const float* W1   = (const float*)d_in[3];
    const float* a_s1 = (const float*)d_in[4];
    const float* a_d1 = (const float*)d_in[5];
    const float* b1   = (const float*)d_in[6];
    const float* W2   = (const float*)d_in[7];
    const float* a_s2 = (const float*)d_in[8];
    const float* a_d2 = (const float*)d_in[9];
    const float* b2   = (const float*)d_in[10];
    float* out = (float*)d_out;

    // workspace layout (111.4 MB):
    //   H1[N,256] | OUT1[N,256] | AS1[N,4] | AD1[N,4] | row_ptr[N] | cnt[N] | fill[N]
    //   | esrc[ET] | ewf[ET] | sums[NCHUNK]
    // layer-2 tensors (H2/AS2/AD2) alias into H1 (dead after agg1_csr).
    float* H1   = (float*)d_ws;
    float* OUT1 = H1 + (size_t)N_NODES * C1;
    float* AS1  = OUT1 + (size_t)N_NODES * C1;
    float* AD1  = AS1 + N_NODES * HEADS;
    int* row_ptr = (int*)(AD1 + N_NODES * HEADS);
    int* cnt  = row_ptr + N_NODES;
    int* fill = cnt + N_NODES;
    int* esrc = fill + N_NODES;
    float* ewf = (float*)(esrc + ET);
    int* sums = (int*)(ewf + ET);
    float* H2  = H1;                       // alias (H1 dead before gemm2 writes)
    float* AS2 = H2 + (size_t)N_NODES * NCLS;
    float* AD2 = AS2 + N_NODES;

    // ---- CSR build ----
    hipMemsetAsync(cnt, 0, N_NODES * sizeof(int), stream);
    hist_kernel<<<(ET + 255) / 256, 256, 0, stream>>>(ei, cnt);
    chunk_sum_kernel<<<NCHUNK, 256, 0, stream>>>(cnt, sums);
    scan_sums_kernel<<<1, 64, 0, stream>>>(sums);
    rowptr_kernel<<<NCHUNK, 256, 0, stream>>>(cnt, sums, row_ptr, fill);
    scatter_kernel<<<(ET + 255) / 256, 256, 0, stream>>>(ei, ew, fill, esrc, ewf);

    // ---- layer 1 ----
    gemm1_kernel<<<dim3(C1 / 64, (N_NODES + 63) / 64), dim3(16, 16), 0, stream>>>(x, W1, H1);
    alphas1_kernel<<<(N_NODES * HEADS + 255) / 256, 256, 0, stream>>>(H1, a_s1, a_d1, AS1, AD1);
    agg1_csr_kernel<<<N_NODES, 256, 0, stream>>>(row_ptr, esrc, ewf, AS1, AD1, H1, b1, OUT1);

    // ---- layer 2 ----
    gemm2_kernel<<<(N_NODES + 3) / 4, 256, 0, stream>>>(OUT1, W2, H2);
    alphas2_kernel<<<(N_NODES + 255) / 256, 256, 0, stream>>>(H2, a_s2, a_d2, AS2, AD2);
    agg2_csr_kernel<<<(N_NODES + 3) / 4, 256, 0, stream>>>(row_ptr, esrc, ewf, AS2, AD2, H2, b2, out);
}

// Round 3
// 739.781 us; speedup vs baseline: 5.0376x; 1.2229x over previous
//
#include <hip/hip_runtime.h>
#include <math.h>

#define N_NODES 50000
#define N_EDGES 800000
#define ET (N_EDGES + N_NODES)   /* 850000 edges incl. self-loops */
#define F_IN 512
#define HID 64
#define HEADS 4
#define C1 (HEADS * HID)         /* 256 */
#define NCLS 40
#define NEG_SLOPE 0.2f
#define NCHUNK ((N_NODES + 255) / 256)   /* 196 */

typedef __attribute__((ext_vector_type(8))) short short8;
typedef __attribute__((ext_vector_type(4))) float floatx4;

__device__ __forceinline__ float leaky(float x) { return x >= 0.f ? x : NEG_SLOPE * x; }

// f32 -> bf16 round-to-nearest-even
__device__ __forceinline__ short f2bf(float f) {
    unsigned u = __float_as_uint(f);
    u += 0x7fffu + ((u >> 16) & 1u);
    return (short)(u >> 16);
}

__device__ __forceinline__ void edge_sd(int e, const int* __restrict__ ei,
                                        const float* __restrict__ ew,
                                        int& s, int& d, float& w) {
    if (e < N_EDGES) { s = ei[e]; d = ei[N_EDGES + e]; w = ew[e]; }
    else             { s = d = e - N_EDGES; w = 1.f; }
}

// ======================= CSR construction (per call) =======================
__global__ void hist_kernel(const int* __restrict__ ei, int* __restrict__ cnt) {
    int e = blockIdx.x * blockDim.x + threadIdx.x;
    if (e >= ET) return;
    int d = (e < N_EDGES) ? ei[N_EDGES + e] : e - N_EDGES;
    atomicAdd(&cnt[d], 1);
}

__global__ void chunk_sum_kernel(const int* __restrict__ cnt, int* __restrict__ sums) {
    __shared__ int sm[256];
    int i = blockIdx.x * 256 + threadIdx.x;
    sm[threadIdx.x] = (i < N_NODES) ? cnt[i] : 0;
    __syncthreads();
    for (int s = 128; s > 0; s >>= 1) {
        if (threadIdx.x < s) sm[threadIdx.x] += sm[threadIdx.x + s];
        __syncthreads();
    }
    if (threadIdx.x == 0) sums[blockIdx.x] = sm[0];
}

__global__ void scan_sums_kernel(int* __restrict__ sums) {
    if (threadIdx.x == 0) {
        int acc = 0;
        for (int i = 0; i < NCHUNK; i++) { int v = sums[i]; sums[i] = acc; acc += v; }
    }
}

__global__ void rowptr_kernel(const int* __restrict__ cnt, const int* __restrict__ sums,
                              int* __restrict__ row_ptr, int* __restrict__ fill) {
    __shared__ int sm[256];
    int i = blockIdx.x * 256 + threadIdx.x;
    int v = (i < N_NODES) ? cnt[i] : 0;
    sm[threadIdx.x] = v;
    __syncthreads();
    #pragma unroll
    for (int s = 1; s < 256; s <<= 1) {
        int t = (threadIdx.x >= s) ? sm[threadIdx.x - s] : 0;
        __syncthreads();
        sm[threadIdx.x] += t;
        __syncthreads();
    }
    int excl = sm[threadIdx.x] - v + sums[blockIdx.x];
    if (i < N_NODES) { row_ptr[i] = excl; fill[i] = excl; }
}

__global__ void scatter_kernel(const int* __restrict__ ei, const float* __restrict__ ew,
                               int* __restrict__ fill, int* __restrict__ esrc,
                               float* __restrict__ ewf) {
    int e = blockIdx.x * blockDim.x + threadIdx.x;
    if (e >= ET) return;
    int s, d; float w;
    edge_sd(e, ei, ew, s, d, w);
    int pos = atomicAdd(&fill[d], 1);
    esrc[pos] = s; ewf[pos] = w;
}

// ============ W1 -> bf16 transpose: WT[n][k] = bf16(W1[k][n]) ============
__global__ void wt_prep_kernel(const float* __restrict__ W, short* __restrict__ WT) {
    __shared__ float tile[32][33];
    int k0 = blockIdx.x * 32;                  // 16 blocks
    int n0 = blockIdx.y * 32;                  // 8 blocks
    int tx = threadIdx.x, ty = threadIdx.y;    // 32 x 8
    #pragma unroll
    for (int i = 0; i < 32; i += 8)
        tile[ty + i][tx] = W[(size_t)(k0 + ty + i) * C1 + n0 + tx];
    __syncthreads();
    #pragma unroll
    for (int i = 0; i < 32; i += 8)
        WT[(size_t)(n0 + ty + i) * F_IN + k0 + tx] = f2bf(tile[tx][ty + i]);
}

// ====== GEMM1 (bf16 MFMA): X[50000,512] @ W1[512,256] -> H1[50000,256] ======
// tile: BM=128, BN=256 (full width, X read once), BK=32; 512 threads = 8 waves;
// each wave owns a 64x64 region = 4x4 grid of 16x16x32 MFMAs.
// LDS row stride 40 shorts (80B = 20 banks): frag reads are 16B-aligned
// ds_read_b128, worst bank aliasing 2-way (free).
__global__ __launch_bounds__(512) void gemm1_mfma_kernel(const float* __restrict__ X,
                                                         const short* __restrict__ WT,
                                                         float* __restrict__ H) {
    __shared__ short As[128][40];   // [m][k] 10KB
    __shared__ short Bs[256][40];   // [n][k] 20KB
    const int t = threadIdx.x;
    const int m0 = blockIdx.x * 128;
    const int lane = t & 63;
    const int wave = t >> 6;        // 0..7
    const int wm = wave >> 2;       // 0..1 : 64-row slab
    const int wn = wave & 3;        // 0..3 : 64-col slab
    const int l15 = lane & 15;
    const int quad = lane >> 4;     // 0..3

    // staging assignments
    const int ar = t >> 2;          // A: row 0..127
    const int ac0 = (t & 3) * 8;    //    k-offset 0/8/16/24
    const int gr = m0 + ar;
    const int bn = t >> 1;          // B: n-row 0..255
    const int bc0 = (t & 1) * 16;   //    k-offset 0/16

    floatx4 acc[4][4];
    #pragma unroll
    for (int i = 0; i < 4; i++)
        #pragma unroll
        for (int j = 0; j < 4; j++) acc[i][j] = (floatx4){0.f, 0.f, 0.f, 0.f};

    for (int k0 = 0; k0 < F_IN; k0 += 32) {
        // --- stage A: 128x32 f32 -> bf16 LDS (8 elems/thread) ---
        float xv[8];
        if (gr < N_NODES) {
            const float4* p = (const float4*)(X + (size_t)gr * F_IN + k0 + ac0);
            float4 v0 = p[0], v1 = p[1];
            xv[0] = v0.x; xv[1] = v0.y; xv[2] = v0.z; xv[3] = v0.w;
            xv[4] = v1.x; xv[5] = v1.y; xv[6] = v1.z; xv[7] = v1.w;
        } else {
            #pragma unroll
            for (int i = 0; i < 8; i++) xv[i] = 0.f;
        }
        short8 av;
        #pragma unroll
        for (int i = 0; i < 8; i++) av[i] = f2bf(xv[i]);
        *(short8*)&As[ar][ac0] = av;

        // --- stage B: 256x32 bf16 copy from WT (16 elems/thread) ---
        const short8* q = (const short8*)(WT + (size_t)bn * F_IN + k0 + bc0);
        *(short8*)&Bs[bn][bc0]     = q[0];
        *(short8*)&Bs[bn][bc0 + 8] = q[1];
        __syncthreads();

        // --- fragments + MFMA ---
        short8 a[4], b[4];
        #pragma unroll
        for (int i = 0; i < 4; i++)
            a[i] = *(const short8*)&As[wm * 64 + i * 16 + l15][quad * 8];
        #pragma unroll
        for (int j = 0; j < 4; j++)
            b[j] = *(const short8*)&Bs[wn * 64 + j * 16 + l15][quad * 8];
        #pragma unroll
        for (int i = 0; i < 4; i++)
            #pragma unroll
            for (int j = 0; j < 4; j++)
                acc[i][j] = __builtin_amdgcn_mfma_f32_16x16x32_bf16(a[i], b[j], acc[i][j], 0, 0, 0);
        __syncthreads();
    }

    // epilogue: D row = quad*4+reg, col = lane&15
    #pragma unroll
    for (int i = 0; i < 4; i++) {
        int rbase = m0 + wm * 64 + i * 16 + quad * 4;
        #pragma unroll
        for (int j = 0; j < 4; j++) {
            int col = wn * 64 + j * 16 + l15;
            #pragma unroll
            for (int r = 0; r < 4; r++) {
                int row = rbase + r;
                if (row < N_NODES) H[(size_t)row * C1 + col] = acc[i][j][r];
            }
        }
    }
}

// -------- per-(node,head) attention logits --------
__global__ void alphas1_kernel(const float* __restrict__ H, const float* __restrict__ a_src,
                               const float* __restrict__ a_dst, float* __restrict__ AS,
                               float* __restrict__ AD) {
    int t = blockIdx.x * blockDim.x + threadIdx.x;
    if (t >= N_NODES * HEADS) return;
    int n = t >> 2, h = t & 3;
    const float* hp = H + (size_t)n * C1 + h * HID;
    const float* sp = a_src + h * HID;
    const float* dp = a_dst + h * HID;
    float s = 0.f, d = 0.f;
    #pragma unroll 16
    for (int k = 0; k < HID; k++) { float v = hp[k]; s += v * sp[k]; d += v * dp[k]; }
    AS[t] = s; AD[t] = d;
}

// ---- fused CSR aggregation layer1: denom + weighted sum + bias + ReLU ----
__global__ __launch_bounds__(256) void agg1_csr_kernel(const int* __restrict__ row_ptr,
                                                       const int* __restrict__ esrc,
                                                       const float* __restrict__ ewf,
                                                       const float* __restrict__ AS,
                                                       const float* __restrict__ AD,
                                                       const float* __restrict__ H,
                                                       const float* __restrict__ b1,
                                                       float* __restrict__ OUT) {
    int n = blockIdx.x;                 // one block per dst node
    int c = threadIdx.x;                // channel 0..255
    int h = c >> 6;                     // head
    int beg = row_ptr[n];
    int end = (n + 1 < N_NODES) ? row_ptr[n + 1] : ET;
    float ad = AD[n * 4 + h];
    float den = 0.f, acc = 0.f;
    for (int p = beg; p < end; p++) {
        int s = esrc[p];
        float w = ewf[p];
        float pe = __expf(leaky(AS[s * 4 + h] + ad));
        den += pe;
        acc += pe * w * H[(size_t)s * C1 + c];
    }
    float v = acc / (den + 1e-16f) + b1[c];
    OUT[(size_t)n * C1 + c] = v > 0.f ? v : 0.f;
}

// ---------------- GEMM2: H[50000,256] @ W2[256,40] -> H2[50000,40] ----------------
__global__ __launch_bounds__(256) void gemm2_kernel(const float* __restrict__ H,
                                                    const float* __restrict__ W2,
                                                    float* __restrict__ H2) {
    __shared__ float Ws[C1 * NCLS];
    for (int i = threadIdx.x; i < C1 * NCLS; i += 256) Ws[i] = W2[i];
    __syncthreads();
    int wave = threadIdx.x >> 6, lane = threadIdx.x & 63;
    int n = blockIdx.x * 4 + wave;
    if (n >= N_NODES || lane >= NCLS) return;
    const float* hp = H + (size_t)n * C1;
    float acc = 0.f;
    for (int k = 0; k < C1; k += 4) {
        float4 hv = *(const float4*)(hp + k);
        acc += hv.x * Ws[(k + 0) * NCLS + lane] + hv.y * Ws[(k + 1) * NCLS + lane]
             + hv.z * Ws[(k + 2) * NCLS + lane] + hv.w * Ws[(k + 3) * NCLS + lane];
    }
    H2[(size_t)n * NCLS + lane] = acc;
}

__global__ void alphas2_kernel(const float* __restrict__ H2, const float* __restrict__ a_src,
                               const float* __restrict__ a_dst, float* __restrict__ AS,
                               float* __restrict__ AD) {
    int n = blockIdx.x * blockDim.x + threadIdx.x;
    if (n >= N_NODES) return;
    float s = 0.f, d = 0.f;
    #pragma unroll
    for (int k = 0; k < NCLS; k++) {
        float v = H2[(size_t)n * NCLS + k];
        s += v * a_src[k]; d += v * a_dst[k];
    }
    AS[n] = s; AD[n] = d;
}

// ---- fused CSR aggregation layer2: denom + weighted sum + bias, writes d_out ----
__global__ __launch_bounds__(256) void agg2_csr_kernel(const int* __restrict__ row_ptr,
                                                       const int* __restrict__ esrc,
                                                       const float* __restrict__ ewf,
                                                       const float* __restrict__ AS,
                                                       const float* __restrict__ AD,
                                                       const float* __restrict__ H2,
                                                       const float* __restrict__ b2,
                                                       float* __restrict__ OUT) {
    int lane = threadIdx.x & 63;
    int n = blockIdx.x * 4 + (threadIdx.x >> 6);   // one wave per dst node
    if (n >= N_NODES) return;
    int beg = row_ptr[n];
    int end = (n + 1 < N_NODES) ? row_ptr[n + 1] : ET;
    float ad = AD[n];
    float den = 0.f, acc = 0.f;
    for (int p = beg; p < end; p++) {
        int s = esrc[p];
        float w = ewf[p];
        float pe = __expf(leaky(AS[s] + ad));
        den += pe;
        if (lane < NCLS) acc += pe * w * H2[(size_t)s * NCLS + lane];
    }
    if (lane < NCLS)
        OUT[(size_t)n * NCLS + lane] = acc / (den + 1e-16f) + b2[lane];
}

extern "C" void kernel_launch(void* const* d_in, const int* in_sizes, int n_in,
                              void* d_out, int out_size, void* d_ws, size_t ws_size,
                              hipStream_t stream) {
    const float* x    = (const float*)d_in[0];
    const int*   ei   = (const int*)d_in[1];
    const float* ew   = (const float*)d_in[2];
    const float* W1   = (const float*)d_in[3];
    const float* a_s1 = (const float*)d_in[4];
    const float* a_d1 = (const float*)d_in[5];
    const float* b1   = (const float*)d_in[6];
    const float* W2   = (const float*)d_in[7];
    const float* a_s2 = (const float*)d_in[8];
    const float* a_d2 = (const float*)d_in[9];
    const float* b2   = (const float*)d_in[10];
    float* out = (float*)d_out;

    // workspace layout:
    //   H1[N,256] | OUT1[N,256] | AS1[N,4] | AD1[N,4] | row_ptr[N] | cnt[N] | fill[N]
    //   | esrc[ET] | ewf[ET] | sums[NCHUNK] | WT[256*512 shorts]
    float* H1   = (float*)d_ws;
    float* OUT1 = H1 + (size_t)N_NODES * C1;
    float* AS1  = OUT1 + (size_t)N_NODES * C1;
    float* AD1  = AS1 + N_NODES * HEADS;
    int* row_ptr = (int*)(AD1 + N_NODES * HEADS);
    int* cnt  = row_ptr + N_NODES;
    int* fill = cnt + N_NODES;
    int* esrc = fill + N_NODES;
    float* ewf = (float*)(esrc + ET);
    int* sums = (int*)(ewf + ET);
    short* WT = (short*)(sums + NCHUNK);
    float* H2  = H1;                       // alias (H1 dead before gemm2 writes)
    float* AS2 = H2 + (size_t)N_NODES * NCLS;
    float* AD2 = AS2 + N_NODES;

    // ---- CSR build + weight prep ----
    hipMemsetAsync(cnt, 0, N_NODES * sizeof(int), stream);
    wt_prep_kernel<<<dim3(F_IN / 32, C1 / 32), dim3(32, 8), 0, stream>>>(W1, WT);
    hist_kernel<<<(ET + 255) / 256, 256, 0, stream>>>(ei, cnt);
    chunk_sum_kernel<<<NCHUNK, 256, 0, stream>>>(cnt, sums);
    scan_sums_kernel<<<1, 64, 0, stream>>>(sums);
    rowptr_kernel<<<NCHUNK, 256, 0, stream>>>(cnt, sums, row_ptr, fill);
    scatter_kernel<<<(ET + 255) / 256, 256, 0, stream>>>(ei, ew, fill, esrc, ewf);

    // ---- layer 1 ----
    gemm1_mfma_kernel<<<(N_NODES + 127) / 128, 512, 0, stream>>>(x, WT, H1);
    alphas1_kernel<<<(N_NODES * HEADS + 255) / 256, 256, 0, stream>>>(H1, a_s1, a_d1, AS1, AD1);
    agg1_csr_kernel<<<N_NODES, 256, 0, stream>>>(row_ptr, esrc, ewf, AS1, AD1, H1, b1, OUT1);

    // ---- layer 2 ----
    gemm2_kernel<<<(N_NODES + 3) / 4, 256, 0, stream>>>(OUT1, W2, H2);
    alphas2_kernel<<<(N_NODES + 255) / 256, 256, 0, stream>>>(H2, a_s2, a_d2, AS2, AD2);
    agg2_csr_kernel<<<(N_NODES + 3) / 4, 256, 0, stream>>>(row_ptr, esrc, ewf, AS2, AD2, H2, b2, out);
}

// Round 4
// 619.549 us; speedup vs baseline: 6.0152x; 1.1941x over previous
//
#include <hip/hip_runtime.h>
#include <math.h>

#define N_NODES 50000
#define N_EDGES 800000
#define ET (N_EDGES + N_NODES)   /* 850000 edges incl. self-loops */
#define F_IN 512
#define HID 64
#define HEADS 4
#define C1 (HEADS * HID)         /* 256 */
#define NCLS 40
#define NEG_SLOPE 0.2f
#define NCHUNK ((N_NODES + 255) / 256)   /* 196 */

typedef __attribute__((ext_vector_type(8))) short short8;
typedef __attribute__((ext_vector_type(4))) float floatx4;

__device__ __forceinline__ float leaky(float x) { return x >= 0.f ? x : NEG_SLOPE * x; }

// f32 -> bf16 round-to-nearest-even
__device__ __forceinline__ unsigned short f2bf(float f) {
    unsigned u = __float_as_uint(f);
    u += 0x7fffu + ((u >> 16) & 1u);
    return (unsigned short)(u >> 16);
}
__device__ __forceinline__ float bf2f(unsigned short u) {
    return __uint_as_float(((unsigned)u) << 16);
}

__device__ __forceinline__ void edge_sd(int e, const int* __restrict__ ei,
                                        const float* __restrict__ ew,
                                        int& s, int& d, float& w) {
    if (e < N_EDGES) { s = ei[e]; d = ei[N_EDGES + e]; w = ew[e]; }
    else             { s = d = e - N_EDGES; w = 1.f; }
}

// ======================= CSR construction (per call) =======================
__global__ void hist_kernel(const int* __restrict__ ei, int* __restrict__ cnt) {
    int e = blockIdx.x * blockDim.x + threadIdx.x;
    if (e >= ET) return;
    int d = (e < N_EDGES) ? ei[N_EDGES + e] : e - N_EDGES;
    atomicAdd(&cnt[d], 1);
}

__global__ void chunk_sum_kernel(const int* __restrict__ cnt, int* __restrict__ sums) {
    __shared__ int sm[256];
    int i = blockIdx.x * 256 + threadIdx.x;
    sm[threadIdx.x] = (i < N_NODES) ? cnt[i] : 0;
    __syncthreads();
    for (int s = 128; s > 0; s >>= 1) {
        if (threadIdx.x < s) sm[threadIdx.x] += sm[threadIdx.x + s];
        __syncthreads();
    }
    if (threadIdx.x == 0) sums[blockIdx.x] = sm[0];
}

__global__ void scan_sums_kernel(int* __restrict__ sums) {
    if (threadIdx.x == 0) {
        int acc = 0;
        for (int i = 0; i < NCHUNK; i++) { int v = sums[i]; sums[i] = acc; acc += v; }
    }
}

__global__ void rowptr_kernel(const int* __restrict__ cnt, const int* __restrict__ sums,
                              int* __restrict__ row_ptr, int* __restrict__ fill) {
    __shared__ int sm[256];
    int i = blockIdx.x * 256 + threadIdx.x;
    int v = (i < N_NODES) ? cnt[i] : 0;
    sm[threadIdx.x] = v;
    __syncthreads();
    #pragma unroll
    for (int s = 1; s < 256; s <<= 1) {
        int t = (threadIdx.x >= s) ? sm[threadIdx.x - s] : 0;
        __syncthreads();
        sm[threadIdx.x] += t;
        __syncthreads();
    }
    int excl = sm[threadIdx.x] - v + sums[blockIdx.x];
    if (i < N_NODES) { row_ptr[i] = excl; fill[i] = excl; }
}

__global__ void scatter_kernel(const int* __restrict__ ei, const float* __restrict__ ew,
                               int* __restrict__ fill, int* __restrict__ esrc,
                               float* __restrict__ ewf) {
    int e = blockIdx.x * blockDim.x + threadIdx.x;
    if (e >= ET) return;
    int s, d; float w;
    edge_sd(e, ei, ew, s, d, w);
    int pos = atomicAdd(&fill[d], 1);
    esrc[pos] = s; ewf[pos] = w;
}

// ============ W1 -> bf16 transpose: WT[n][k] = bf16(W1[k][n]) ============
__global__ void wt_prep_kernel(const float* __restrict__ W, unsigned short* __restrict__ WT) {
    __shared__ float tile[32][33];
    int k0 = blockIdx.x * 32;
    int n0 = blockIdx.y * 32;
    int tx = threadIdx.x, ty = threadIdx.y;    // 32 x 8
    #pragma unroll
    for (int i = 0; i < 32; i += 8)
        tile[ty + i][tx] = W[(size_t)(k0 + ty + i) * C1 + n0 + tx];
    __syncthreads();
    #pragma unroll
    for (int i = 0; i < 32; i += 8)
        WT[(size_t)(n0 + ty + i) * F_IN + k0 + tx] = f2bf(tile[tx][ty + i]);
}

// ====== GEMM1 (bf16 MFMA): X[50000,512] @ W1[512,256] -> H1 (bf16) ======
__global__ __launch_bounds__(512) void gemm1_mfma_kernel(const float* __restrict__ X,
                                                         const unsigned short* __restrict__ WT,
                                                         unsigned short* __restrict__ H) {
    __shared__ short As[128][40];
    __shared__ short Bs[256][40];
    const int t = threadIdx.x;
    const int m0 = blockIdx.x * 128;
    const int lane = t & 63;
    const int wave = t >> 6;
    const int wm = wave >> 2;
    const int wn = wave & 3;
    const int l15 = lane & 15;
    const int quad = lane >> 4;

    const int ar = t >> 2;
    const int ac0 = (t & 3) * 8;
    const int gr = m0 + ar;
    const int bn = t >> 1;
    const int bc0 = (t & 1) * 16;

    floatx4 acc[4][4];
    #pragma unroll
    for (int i = 0; i < 4; i++)
        #pragma unroll
        for (int j = 0; j < 4; j++) acc[i][j] = (floatx4){0.f, 0.f, 0.f, 0.f};

    for (int k0 = 0; k0 < F_IN; k0 += 32) {
        float xv[8];
        if (gr < N_NODES) {
            const float4* p = (const float4*)(X + (size_t)gr * F_IN + k0 + ac0);
            float4 v0 = p[0], v1 = p[1];
            xv[0] = v0.x; xv[1] = v0.y; xv[2] = v0.z; xv[3] = v0.w;
            xv[4] = v1.x; xv[5] = v1.y; xv[6] = v1.z; xv[7] = v1.w;
        } else {
            #pragma unroll
            for (int i = 0; i < 8; i++) xv[i] = 0.f;
        }
        short8 av;
        #pragma unroll
        for (int i = 0; i < 8; i++) av[i] = (short)f2bf(xv[i]);
        *(short8*)&As[ar][ac0] = av;

        const short8* q = (const short8*)(WT + (size_t)bn * F_IN + k0 + bc0);
        *(short8*)&Bs[bn][bc0]     = q[0];
        *(short8*)&Bs[bn][bc0 + 8] = q[1];
        __syncthreads();

        short8 a[4], b[4];
        #pragma unroll
        for (int i = 0; i < 4; i++)
            a[i] = *(const short8*)&As[wm * 64 + i * 16 + l15][quad * 8];
        #pragma unroll
        for (int j = 0; j < 4; j++)
            b[j] = *(const short8*)&Bs[wn * 64 + j * 16 + l15][quad * 8];
        #pragma unroll
        for (int i = 0; i < 4; i++)
            #pragma unroll
            for (int j = 0; j < 4; j++)
                acc[i][j] = __builtin_amdgcn_mfma_f32_16x16x32_bf16(a[i], b[j], acc[i][j], 0, 0, 0);
        __syncthreads();
    }

    #pragma unroll
    for (int i = 0; i < 4; i++) {
        int rbase = m0 + wm * 64 + i * 16 + quad * 4;
        #pragma unroll
        for (int j = 0; j < 4; j++) {
            int col = wn * 64 + j * 16 + l15;
            #pragma unroll
            for (int r = 0; r < 4; r++) {
                int row = rbase + r;
                if (row < N_NODES) H[(size_t)row * C1 + col] = f2bf(acc[i][j][r]);
            }
        }
    }
}

// -------- per-(node,head) attention logits (bf16 H) --------
__global__ void alphas1_kernel(const unsigned short* __restrict__ H,
                               const float* __restrict__ a_src,
                               const float* __restrict__ a_dst,
                               float* __restrict__ AS, float* __restrict__ AD) {
    int t = blockIdx.x * blockDim.x + threadIdx.x;
    if (t >= N_NODES * HEADS) return;
    int n = t >> 2, h = t & 3;
    const unsigned* hp = (const unsigned*)(H + (size_t)n * C1 + h * HID);
    const float* sp = a_src + h * HID;
    const float* dp = a_dst + h * HID;
    float s = 0.f, d = 0.f;
    #pragma unroll 8
    for (int k = 0; k < HID / 2; k++) {
        unsigned u = hp[k];
        float v0 = __uint_as_float(u << 16);
        float v1 = __uint_as_float(u & 0xffff0000u);
        s += v0 * sp[2 * k] + v1 * sp[2 * k + 1];
        d += v0 * dp[2 * k] + v1 * dp[2 * k + 1];
    }
    AS[t] = s; AD[t] = d;
}

// ---- per-edge normalized alpha (4 heads), CSR order; wave per node ----
__global__ __launch_bounds__(256) void alpha1_prep_kernel(const int* __restrict__ row_ptr,
                                                          const int* __restrict__ esrc,
                                                          const float* __restrict__ ewf,
                                                          const float* __restrict__ AS,
                                                          const float* __restrict__ AD,
                                                          floatx4* __restrict__ ALF) {
    int lane = threadIdx.x & 63;
    int n = blockIdx.x * 4 + (threadIdx.x >> 6);
    if (n >= N_NODES) return;
    int beg = row_ptr[n];
    int end = (n + 1 < N_NODES) ? row_ptr[n + 1] : ET;
    const float4 ad = *(const float4*)(AD + n * 4);
    float dx = 0.f, dy = 0.f, dz = 0.f, dw = 0.f;
    for (int p = beg + lane; p < end; p += 64) {
        const float4 as = *(const float4*)(AS + esrc[p] * 4);
        dx += __expf(leaky(as.x + ad.x));
        dy += __expf(leaky(as.y + ad.y));
        dz += __expf(leaky(as.z + ad.z));
        dw += __expf(leaky(as.w + ad.w));
    }
    #pragma unroll
    for (int m = 32; m; m >>= 1) {
        dx += __shfl_xor(dx, m); dy += __shfl_xor(dy, m);
        dz += __shfl_xor(dz, m); dw += __shfl_xor(dw, m);
    }
    float rx = 1.f / (dx + 1e-16f), ry = 1.f / (dy + 1e-16f);
    float rz = 1.f / (dz + 1e-16f), rw = 1.f / (dw + 1e-16f);
    for (int p = beg + lane; p < end; p += 64) {
        const float4 as = *(const float4*)(AS + esrc[p] * 4);
        float w = ewf[p];
        floatx4 a;
        a[0] = __expf(leaky(as.x + ad.x)) * w * rx;
        a[1] = __expf(leaky(as.y + ad.y)) * w * ry;
        a[2] = __expf(leaky(as.z + ad.z)) * w * rz;
        a[3] = __expf(leaky(as.w + ad.w)) * w * rw;
        ALF[p] = a;
    }
}

// ---- agg1: 2 nodes/block, 128 threads/node, 2 channels/thread, bf16 gather ----
__global__ __launch_bounds__(256) void agg1_csr_kernel(const int* __restrict__ row_ptr,
                                                       const int* __restrict__ esrc,
                                                       const floatx4* __restrict__ ALF,
                                                       const unsigned short* __restrict__ H,
                                                       const float* __restrict__ b1,
                                                       float* __restrict__ OUT) {
    int n = blockIdx.x * 2 + (threadIdx.x >> 7);
    int tl = threadIdx.x & 127;
    if (n >= N_NODES) return;
    int c0 = tl * 2;
    int h = c0 >> 6;
    int beg = row_ptr[n];
    int end = (n + 1 < N_NODES) ? row_ptr[n + 1] : ET;
    float a0 = 0.f, a1 = 0.f;
    int p = beg;
    for (; p + 1 < end; p += 2) {
        int s0 = esrc[p], s1 = esrc[p + 1];
        float al0 = ((const float*)&ALF[p])[h];
        float al1 = ((const float*)&ALF[p + 1])[h];
        unsigned u0 = *(const unsigned*)(H + (size_t)s0 * C1 + c0);
        unsigned u1 = *(const unsigned*)(H + (size_t)s1 * C1 + c0);
        a0 += al0 * __uint_as_float(u0 << 16) + al1 * __uint_as_float(u1 << 16);
        a1 += al0 * __uint_as_float(u0 & 0xffff0000u) + al1 * __uint_as_float(u1 & 0xffff0000u);
    }
    if (p < end) {
        int s0 = esrc[p];
        float al0 = ((const float*)&ALF[p])[h];
        unsigned u0 = *(const unsigned*)(H + (size_t)s0 * C1 + c0);
        a0 += al0 * __uint_as_float(u0 << 16);
        a1 += al0 * __uint_as_float(u0 & 0xffff0000u);
    }
    float v0 = a0 + b1[c0];
    float v1 = a1 + b1[c0 + 1];
    float2 o;
    o.x = v0 > 0.f ? v0 : 0.f;
    o.y = v1 > 0.f ? v1 : 0.f;
    *(float2*)(OUT + (size_t)n * C1 + c0) = o;
}

// ---- GEMM2 + fused alphas2: H[50000,256]@W2[256,40], AS2/AD2 via wave reduce ----
__global__ __launch_bounds__(256) void gemm2_fused_kernel(const float* __restrict__ H,
                                                          const float* __restrict__ W2,
                                                          const float* __restrict__ a_s2,
                                                          const float* __restrict__ a_d2,
                                                          float* __restrict__ H2,
                                                          float* __restrict__ AS2,
                                                          float* __restrict__ AD2) {
    __shared__ float Ws[C1 * NCLS];
    for (int i = threadIdx.x; i < C1 * NCLS; i += 256) Ws[i] = W2[i];
    __syncthreads();
    int wave = threadIdx.x >> 6, lane = threadIdx.x & 63;
    int n = blockIdx.x * 4 + wave;
    if (n >= N_NODES) return;   // wave-uniform exit
    float acc = 0.f;
    if (lane < NCLS) {
        const float* hp = H + (size_t)n * C1;
        for (int k = 0; k < C1; k += 4) {
            float4 hv = *(const float4*)(hp + k);
            acc += hv.x * Ws[(k + 0) * NCLS + lane] + hv.y * Ws[(k + 1) * NCLS + lane]
                 + hv.z * Ws[(k + 2) * NCLS + lane] + hv.w * Ws[(k + 3) * NCLS + lane];
        }
    }
    float s_ = (lane < NCLS) ? acc * a_s2[lane] : 0.f;
    float d_ = (lane < NCLS) ? acc * a_d2[lane] : 0.f;
    #pragma unroll
    for (int m = 32; m; m >>= 1) { s_ += __shfl_xor(s_, m); d_ += __shfl_xor(d_, m); }
    if (lane == 0) { AS2[n] = s_; AD2[n] = d_; }
    if (lane < NCLS) H2[(size_t)n * NCLS + lane] = acc;
}

// ---- per-edge normalized alpha layer2 ----
__global__ __launch_bounds__(256) void alpha2_prep_kernel(const int* __restrict__ row_ptr,
                                                          const int* __restrict__ esrc,
                                                          const float* __restrict__ ewf,
                                                          const float* __restrict__ AS,
                                                          const float* __restrict__ AD,
                                                          float* __restrict__ ALF2) {
    int lane = threadIdx.x & 63;
    int n = blockIdx.x * 4 + (threadIdx.x >> 6);
    if (n >= N_NODES) return;
    int beg = row_ptr[n];
    int end = (n + 1 < N_NODES) ? row_ptr[n + 1] : ET;
    float ad = AD[n];
    float den = 0.f;
    for (int p = beg + lane; p < end; p += 64)
        den += __expf(leaky(AS[esrc[p]] + ad));
    #pragma unroll
    for (int m = 32; m; m >>= 1) den += __shfl_xor(den, m);
    float r = 1.f / (den + 1e-16f);
    for (int p = beg + lane; p < end; p += 64)
        ALF2[p] = __expf(leaky(AS[esrc[p]] + ad)) * ewf[p] * r;
}

// ---- agg2: wave per node, precomputed alpha, writes d_out ----
__global__ __launch_bounds__(256) void agg2_csr_kernel(const int* __restrict__ row_ptr,
                                                       const int* __restrict__ esrc,
                                                       const float* __restrict__ ALF2,
                                                       const float* __restrict__ H2,
                                                       const float* __restrict__ b2,
                                                       float* __restrict__ OUT) {
    int lane = threadIdx.x & 63;
    int n = blockIdx.x * 4 + (threadIdx.x >> 6);
    if (n >= N_NODES) return;
    int beg = row_ptr[n];
    int end = (n + 1 < N_NODES) ? row_ptr[n + 1] : ET;
    float acc = 0.f;
    int p = beg;
    for (; p + 1 < end; p += 2) {
        int s0 = esrc[p], s1 = esrc[p + 1];
        float al0 = ALF2[p], al1 = ALF2[p + 1];
        if (lane < NCLS)
            acc += al0 * H2[(size_t)s0 * NCLS + lane] + al1 * H2[(size_t)s1 * NCLS + lane];
    }
    if (p < end) {
        int s0 = esrc[p];
        float al0 = ALF2[p];
        if (lane < NCLS) acc += al0 * H2[(size_t)s0 * NCLS + lane];
    }
    if (lane < NCLS)
        OUT[(size_t)n * NCLS + lane] = acc + b2[lane];
}

extern "C" void kernel_launch(void* const* d_in, const int* in_sizes, int n_in,
                              void* d_out, int out_size, void* d_ws, size_t ws_size,
                              hipStream_t stream) {
    const float* x    = (const float*)d_in[0];
    const int*   ei   = (const int*)d_in[1];
    const float* ew   = (const float*)d_in[2];
    const float* W1   = (const float*)d_in[3];
    const float* a_s1 = (const float*)d_in[4];
    const float* a_d1 = (const float*)d_in[5];
    const float* b1   = (const float*)d_in[6];
    const float* W2   = (const float*)d_in[7];
    const float* a_s2 = (const float*)d_in[8];
    const float* a_d2 = (const float*)d_in[9];
    const float* b2   = (const float*)d_in[10];
    float* out = (float*)d_out;

    // workspace (~100 MB):
    //  H1b[N*256 bf16] | OUT1[N*256 f32] | AS1[N*4] | AD1[N*4] | ALF1[ET float4]
    //  | row_ptr[N] | cnt[N] | fill[N] | esrc[ET] | ewf[ET] | sums | WT[256*512 bf16]
    //  layer2 (H2/AS2/AD2/ALF2) aliases into the H1b region (dead after agg1).
    unsigned short* H1b = (unsigned short*)d_ws;
    float* OUT1 = (float*)(H1b + (size_t)N_NODES * C1);
    float* AS1  = OUT1 + (size_t)N_NODES * C1;
    float* AD1  = AS1 + N_NODES * HEADS;
    floatx4* ALF1 = (floatx4*)(AD1 + N_NODES * HEADS);
    int* row_ptr = (int*)(ALF1 + ET);
    int* cnt  = row_ptr + N_NODES;
    int* fill = cnt + N_NODES;
    int* esrc = fill + N_NODES;
    float* ewf = (float*)(esrc + ET);
    int* sums = (int*)(ewf + ET);
    unsigned short* WT = (unsigned short*)(sums + NCHUNK);
    float* H2   = (float*)H1b;             // alias
    float* AS2  = H2 + (size_t)N_NODES * NCLS;
    float* AD2  = AS2 + N_NODES;
    float* ALF2 = AD2 + N_NODES;

    // ---- CSR build + weight prep ----
    hipMemsetAsync(cnt, 0, N_NODES * sizeof(int), stream);
    wt_prep_kernel<<<dim3(F_IN / 32, C1 / 32), dim3(32, 8), 0, stream>>>(W1, WT);
    hist_kernel<<<(ET + 255) / 256, 256, 0, stream>>>(ei, cnt);
    chunk_sum_kernel<<<NCHUNK, 256, 0, stream>>>(cnt, sums);
    scan_sums_kernel<<<1, 64, 0, stream>>>(sums);
    rowptr_kernel<<<NCHUNK, 256, 0, stream>>>(cnt, sums, row_ptr, fill);
    scatter_kernel<<<(ET + 255) / 256, 256, 0, stream>>>(ei, ew, fill, esrc, ewf);

    // ---- layer 1 ----
    gemm1_mfma_kernel<<<(N_NODES + 127) / 128, 512, 0, stream>>>(x, WT, H1b);
    alphas1_kernel<<<(N_NODES * HEADS + 255) / 256, 256, 0, stream>>>(H1b, a_s1, a_d1, AS1, AD1);
    alpha1_prep_kernel<<<(N_NODES + 3) / 4, 256, 0, stream>>>(row_ptr, esrc, ewf, AS1, AD1, ALF1);
    agg1_csr_kernel<<<(N_NODES + 1) / 2, 256, 0, stream>>>(row_ptr, esrc, ALF1, H1b, b1, OUT1);

    // ---- layer 2 ----
    gemm2_fused_kernel<<<(N_NODES + 3) / 4, 256, 0, stream>>>(OUT1, W2, a_s2, a_d2, H2, AS2, AD2);
    alpha2_prep_kernel<<<(N_NODES + 3) / 4, 256, 0, stream>>>(row_ptr, esrc, ewf, AS2, AD2, ALF2);
    agg2_csr_kernel<<<(N_NODES + 3) / 4, 256, 0, stream>>>(row_ptr, esrc, ALF2, H2, b2, out);
}

// Round 5
// 515.148 us; speedup vs baseline: 7.2342x; 1.2027x over previous
//
#include <hip/hip_runtime.h>
#include <math.h>

#define N_NODES 50000
#define N_EDGES 800000
#define ET (N_EDGES + N_NODES)   /* 850000 edges incl. self-loops */
#define F_IN 512
#define HID 64
#define HEADS 4
#define C1 (HEADS * HID)         /* 256 */
#define NCLS 40
#define NEG_SLOPE 0.2f
#define NCHUNK ((N_NODES + 255) / 256)   /* 196 */

typedef __attribute__((ext_vector_type(8))) short short8;
typedef __attribute__((ext_vector_type(4))) float floatx4;

__device__ __forceinline__ float leaky(float x) { return x >= 0.f ? x : NEG_SLOPE * x; }

// f32 -> bf16 round-to-nearest-even
__device__ __forceinline__ unsigned short f2bf(float f) {
    unsigned u = __float_as_uint(f);
    u += 0x7fffu + ((u >> 16) & 1u);
    return (unsigned short)(u >> 16);
}

__device__ __forceinline__ void edge_sd(int e, const int* __restrict__ ei,
                                        const float* __restrict__ ew,
                                        int& s, int& d, float& w) {
    if (e < N_EDGES) { s = ei[e]; d = ei[N_EDGES + e]; w = ew[e]; }
    else             { s = d = e - N_EDGES; w = 1.f; }
}

// ======================= CSR construction (per call) =======================
__global__ void hist_kernel(const int* __restrict__ ei, int* __restrict__ cnt) {
    int e = blockIdx.x * blockDim.x + threadIdx.x;
    if (e >= ET) return;
    int d = (e < N_EDGES) ? ei[N_EDGES + e] : e - N_EDGES;
    atomicAdd(&cnt[d], 1);
}

__global__ void chunk_sum_kernel(const int* __restrict__ cnt, int* __restrict__ sums) {
    __shared__ int sm[256];
    int i = blockIdx.x * 256 + threadIdx.x;
    sm[threadIdx.x] = (i < N_NODES) ? cnt[i] : 0;
    __syncthreads();
    for (int s = 128; s > 0; s >>= 1) {
        if (threadIdx.x < s) sm[threadIdx.x] += sm[threadIdx.x + s];
        __syncthreads();
    }
    if (threadIdx.x == 0) sums[blockIdx.x] = sm[0];
}

__global__ void scan_sums_kernel(int* __restrict__ sums) {
    if (threadIdx.x == 0) {
        int acc = 0;
        for (int i = 0; i < NCHUNK; i++) { int v = sums[i]; sums[i] = acc; acc += v; }
    }
}

__global__ void rowptr_kernel(const int* __restrict__ cnt, const int* __restrict__ sums,
                              int* __restrict__ row_ptr, int* __restrict__ fill) {
    __shared__ int sm[256];
    int i = blockIdx.x * 256 + threadIdx.x;
    int v = (i < N_NODES) ? cnt[i] : 0;
    sm[threadIdx.x] = v;
    __syncthreads();
    #pragma unroll
    for (int s = 1; s < 256; s <<= 1) {
        int t = (threadIdx.x >= s) ? sm[threadIdx.x - s] : 0;
        __syncthreads();
        sm[threadIdx.x] += t;
        __syncthreads();
    }
    int excl = sm[threadIdx.x] - v + sums[blockIdx.x];
    if (i < N_NODES) { row_ptr[i] = excl; fill[i] = excl; }
}

__global__ void scatter_kernel(const int* __restrict__ ei, const float* __restrict__ ew,
                               int* __restrict__ fill, int* __restrict__ esrc,
                               float* __restrict__ ewf) {
    int e = blockIdx.x * blockDim.x + threadIdx.x;
    if (e >= ET) return;
    int s, d; float w;
    edge_sd(e, ei, ew, s, d, w);
    int pos = atomicAdd(&fill[d], 1);
    esrc[pos] = s; ewf[pos] = w;
}

// ============ W1 -> bf16 transpose: WT[n][k] = bf16(W1[k][n]) ============
__global__ void wt_prep_kernel(const float* __restrict__ W, unsigned short* __restrict__ WT) {
    __shared__ float tile[32][33];
    int k0 = blockIdx.x * 32;
    int n0 = blockIdx.y * 32;
    int tx = threadIdx.x, ty = threadIdx.y;    // 32 x 8
    #pragma unroll
    for (int i = 0; i < 32; i += 8)
        tile[ty + i][tx] = W[(size_t)(k0 + ty + i) * C1 + n0 + tx];
    __syncthreads();
    #pragma unroll
    for (int i = 0; i < 32; i += 8)
        WT[(size_t)(n0 + ty + i) * F_IN + k0 + tx] = f2bf(tile[tx][ty + i]);
}

// ====== GEMM1 (bf16 MFMA): X[50000,512] @ W1[512,256] -> H1 (bf16) ======
__global__ __launch_bounds__(512) void gemm1_mfma_kernel(const float* __restrict__ X,
                                                         const unsigned short* __restrict__ WT,
                                                         unsigned short* __restrict__ H) {
    __shared__ short As[128][40];
    __shared__ short Bs[256][40];
    const int t = threadIdx.x;
    const int m0 = blockIdx.x * 128;
    const int lane = t & 63;
    const int wave = t >> 6;
    const int wm = wave >> 2;
    const int wn = wave & 3;
    const int l15 = lane & 15;
    const int quad = lane >> 4;

    const int ar = t >> 2;
    const int ac0 = (t & 3) * 8;
    const int gr = m0 + ar;
    const int bn = t >> 1;
    const int bc0 = (t & 1) * 16;

    floatx4 acc[4][4];
    #pragma unroll
    for (int i = 0; i < 4; i++)
        #pragma unroll
        for (int j = 0; j < 4; j++) acc[i][j] = (floatx4){0.f, 0.f, 0.f, 0.f};

    for (int k0 = 0; k0 < F_IN; k0 += 32) {
        float xv[8];
        if (gr < N_NODES) {
            const float4* p = (const float4*)(X + (size_t)gr * F_IN + k0 + ac0);
            float4 v0 = p[0], v1 = p[1];
            xv[0] = v0.x; xv[1] = v0.y; xv[2] = v0.z; xv[3] = v0.w;
            xv[4] = v1.x; xv[5] = v1.y; xv[6] = v1.z; xv[7] = v1.w;
        } else {
            #pragma unroll
            for (int i = 0; i < 8; i++) xv[i] = 0.f;
        }
        short8 av;
        #pragma unroll
        for (int i = 0; i < 8; i++) av[i] = (short)f2bf(xv[i]);
        *(short8*)&As[ar][ac0] = av;

        const short8* q = (const short8*)(WT + (size_t)bn * F_IN + k0 + bc0);
        *(short8*)&Bs[bn][bc0]     = q[0];
        *(short8*)&Bs[bn][bc0 + 8] = q[1];
        __syncthreads();

        short8 a[4], b[4];
        #pragma unroll
        for (int i = 0; i < 4; i++)
            a[i] = *(const short8*)&As[wm * 64 + i * 16 + l15][quad * 8];
        #pragma unroll
        for (int j = 0; j < 4; j++)
            b[j] = *(const short8*)&Bs[wn * 64 + j * 16 + l15][quad * 8];
        #pragma unroll
        for (int i = 0; i < 4; i++)
            #pragma unroll
            for (int j = 0; j < 4; j++)
                acc[i][j] = __builtin_amdgcn_mfma_f32_16x16x32_bf16(a[i], b[j], acc[i][j], 0, 0, 0);
        __syncthreads();
    }

    #pragma unroll
    for (int i = 0; i < 4; i++) {
        int rbase = m0 + wm * 64 + i * 16 + quad * 4;
        #pragma unroll
        for (int j = 0; j < 4; j++) {
            int col = wn * 64 + j * 16 + l15;
            #pragma unroll
            for (int r = 0; r < 4; r++) {
                int row = rbase + r;
                if (row < N_NODES) H[(size_t)row * C1 + col] = f2bf(acc[i][j][r]);
            }
        }
    }
}

// -------- per-(node,head) attention logits (bf16 H) --------
__global__ void alphas1_kernel(const unsigned short* __restrict__ H,
                               const float* __restrict__ a_src,
                               const float* __restrict__ a_dst,
                               float* __restrict__ AS, float* __restrict__ AD) {
    int t = blockIdx.x * blockDim.x + threadIdx.x;
    if (t >= N_NODES * HEADS) return;
    int n = t >> 2, h = t & 3;
    const unsigned* hp = (const unsigned*)(H + (size_t)n * C1 + h * HID);
    const float* sp = a_src + h * HID;
    const float* dp = a_dst + h * HID;
    float s = 0.f, d = 0.f;
    #pragma unroll 8
    for (int k = 0; k < HID / 2; k++) {
        unsigned u = hp[k];
        float v0 = __uint_as_float(u << 16);
        float v1 = __uint_as_float(u & 0xffff0000u);
        s += v0 * sp[2 * k] + v1 * sp[2 * k + 1];
        d += v0 * dp[2 * k] + v1 * dp[2 * k + 1];
    }
    AS[t] = s; AD[t] = d;
}

// ---- per-edge normalized alpha (4 heads), CSR order; wave per node ----
__global__ __launch_bounds__(256) void alpha1_prep_kernel(const int* __restrict__ row_ptr,
                                                          const int* __restrict__ esrc,
                                                          const float* __restrict__ ewf,
                                                          const float* __restrict__ AS,
                                                          const float* __restrict__ AD,
                                                          floatx4* __restrict__ ALF) {
    int lane = threadIdx.x & 63;
    int n = blockIdx.x * 4 + (threadIdx.x >> 6);
    if (n >= N_NODES) return;
    int beg = row_ptr[n];
    int end = (n + 1 < N_NODES) ? row_ptr[n + 1] : ET;
    const float4 ad = *(const float4*)(AD + n * 4);
    float dx = 0.f, dy = 0.f, dz = 0.f, dw = 0.f;
    for (int p = beg + lane; p < end; p += 64) {
        const float4 as = *(const float4*)(AS + esrc[p] * 4);
        dx += __expf(leaky(as.x + ad.x));
        dy += __expf(leaky(as.y + ad.y));
        dz += __expf(leaky(as.z + ad.z));
        dw += __expf(leaky(as.w + ad.w));
    }
    #pragma unroll
    for (int m = 32; m; m >>= 1) {
        dx += __shfl_xor(dx, m); dy += __shfl_xor(dy, m);
        dz += __shfl_xor(dz, m); dw += __shfl_xor(dw, m);
    }
    float rx = 1.f / (dx + 1e-16f), ry = 1.f / (dy + 1e-16f);
    float rz = 1.f / (dz + 1e-16f), rw = 1.f / (dw + 1e-16f);
    for (int p = beg + lane; p < end; p += 64) {
        const float4 as = *(const float4*)(AS + esrc[p] * 4);
        float w = ewf[p];
        floatx4 a;
        a[0] = __expf(leaky(as.x + ad.x)) * w * rx;
        a[1] = __expf(leaky(as.y + ad.y)) * w * ry;
        a[2] = __expf(leaky(as.z + ad.z)) * w * rz;
        a[3] = __expf(leaky(as.w + ad.w)) * w * rw;
        ALF[p] = a;
    }
}

// ---- agg1: 2 nodes/block, 128 threads/node, 2 channels/thread, bf16 gather,
//      bf16 packed output (feeds MFMA gemm2) ----
__global__ __launch_bounds__(256) void agg1_csr_kernel(const int* __restrict__ row_ptr,
                                                       const int* __restrict__ esrc,
                                                       const floatx4* __restrict__ ALF,
                                                       const unsigned short* __restrict__ H,
                                                       const float* __restrict__ b1,
                                                       unsigned short* __restrict__ OUT) {
    int n = blockIdx.x * 2 + (threadIdx.x >> 7);
    int tl = threadIdx.x & 127;
    if (n >= N_NODES) return;
    int c0 = tl * 2;
    int h = c0 >> 6;
    int beg = row_ptr[n];
    int end = (n + 1 < N_NODES) ? row_ptr[n + 1] : ET;
    float a0 = 0.f, a1 = 0.f;
    int p = beg;
    for (; p + 1 < end; p += 2) {
        int s0 = esrc[p], s1 = esrc[p + 1];
        float al0 = ((const float*)&ALF[p])[h];
        float al1 = ((const float*)&ALF[p + 1])[h];
        unsigned u0 = *(const unsigned*)(H + (size_t)s0 * C1 + c0);
        unsigned u1 = *(const unsigned*)(H + (size_t)s1 * C1 + c0);
        a0 += al0 * __uint_as_float(u0 << 16) + al1 * __uint_as_float(u1 << 16);
        a1 += al0 * __uint_as_float(u0 & 0xffff0000u) + al1 * __uint_as_float(u1 & 0xffff0000u);
    }
    if (p < end) {
        int s0 = esrc[p];
        float al0 = ((const float*)&ALF[p])[h];
        unsigned u0 = *(const unsigned*)(H + (size_t)s0 * C1 + c0);
        a0 += al0 * __uint_as_float(u0 << 16);
        a1 += al0 * __uint_as_float(u0 & 0xffff0000u);
    }
    float v0 = a0 + b1[c0];
    float v1 = a1 + b1[c0 + 1];
    v0 = v0 > 0.f ? v0 : 0.f;
    v1 = v1 > 0.f ? v1 : 0.f;
    unsigned o = ((unsigned)f2bf(v1) << 16) | (unsigned)f2bf(v0);
    *(unsigned*)(OUT + (size_t)n * C1 + c0) = o;
}

// ====== GEMM2 (bf16 MFMA): OUT1b[50000,256] @ W2[256,40] -> H2 (f32) ======
// BM=256, 8 waves x (2 row-tiles x 3 col-tiles of 16x16x32). W2 transposed
// + bf16-cast into LDS once per block (cols 40..47 zero pad).
#define BROW 264   /* LDS row stride for Bs2: 528B = 33*16, 16B-aligned */
__global__ __launch_bounds__(512) void gemm2_mfma_kernel(const unsigned short* __restrict__ A,
                                                         const float* __restrict__ W2,
                                                         float* __restrict__ H2) {
    __shared__ short As[256][40];        // 20 KB
    __shared__ short Bs[48 * BROW];      // 25.3 KB
    const int t = threadIdx.x;
    const int m0 = blockIdx.x * 256;
    const int lane = t & 63;
    const int wave = t >> 6;             // 0..7 : 32-row slab
    const int l15 = lane & 15;
    const int quad = lane >> 4;

    // stage W2^T (bf16) once: Bs[n*BROW + k] = bf16(W2[k*40+n]), n<48 pad 0
    for (int i = t; i < 48 * 256; i += 512) {
        int n = i >> 8, k = i & 255;
        float v = (n < NCLS) ? W2[k * NCLS + n] : 0.f;
        Bs[n * BROW + k] = (short)f2bf(v);
    }

    const int ar = t >> 1;               // A staging: row 0..255
    const int ac0 = (t & 1) * 16;        // k-offset 0/16

    floatx4 acc[2][3];
    #pragma unroll
    for (int i = 0; i < 2; i++)
        #pragma unroll
        for (int j = 0; j < 3; j++) acc[i][j] = (floatx4){0.f, 0.f, 0.f, 0.f};

    for (int k0 = 0; k0 < C1; k0 += 32) {
        const short8* q = (const short8*)(A + (size_t)(m0 + ar) * C1 + k0 + ac0);
        short8 v0 = q[0], v1 = q[1];
        __syncthreads();                 // Bs ready (first iter) / prev reads done
        *(short8*)&As[ar][ac0]     = v0;
        *(short8*)&As[ar][ac0 + 8] = v1;
        __syncthreads();

        short8 a[2], b[3];
        #pragma unroll
        for (int i = 0; i < 2; i++)
            a[i] = *(const short8*)&As[wave * 32 + i * 16 + l15][quad * 8];
        #pragma unroll
        for (int j = 0; j < 3; j++)
            b[j] = *(const short8*)&Bs[(j * 16 + l15) * BROW + k0 + quad * 8];
        #pragma unroll
        for (int i = 0; i < 2; i++)
            #pragma unroll
            for (int j = 0; j < 3; j++)
                acc[i][j] = __builtin_amdgcn_mfma_f32_16x16x32_bf16(a[i], b[j], acc[i][j], 0, 0, 0);
    }

    #pragma unroll
    for (int i = 0; i < 2; i++) {
        int rbase = m0 + wave * 32 + i * 16 + quad * 4;
        #pragma unroll
        for (int j = 0; j < 3; j++) {
            int col = j * 16 + l15;
            if (col < NCLS) {
                #pragma unroll
                for (int r = 0; r < 4; r++) {
                    int row = rbase + r;
                    if (row < N_NODES) H2[(size_t)row * NCLS + col] = acc[i][j][r];
                }
            }
        }
    }
}

__global__ void alphas2_kernel(const float* __restrict__ H2, const float* __restrict__ a_src,
                               const float* __restrict__ a_dst, float* __restrict__ AS,
                               float* __restrict__ AD) {
    int n = blockIdx.x * blockDim.x + threadIdx.x;
    if (n >= N_NODES) return;
    float s = 0.f, d = 0.f;
    #pragma unroll
    for (int k = 0; k < NCLS; k++) {
        float v = H2[(size_t)n * NCLS + k];
        s += v * a_src[k]; d += v * a_dst[k];
    }
    AS[n] = s; AD[n] = d;
}

// ---- per-edge normalized alpha layer2 ----
__global__ __launch_bounds__(256) void alpha2_prep_kernel(const int* __restrict__ row_ptr,
                                                          const int* __restrict__ esrc,
                                                          const float* __restrict__ ewf,
                                                          const float* __restrict__ AS,
                                                          const float* __restrict__ AD,
                                                          float* __restrict__ ALF2) {
    int lane = threadIdx.x & 63;
    int n = blockIdx.x * 4 + (threadIdx.x >> 6);
    if (n >= N_NODES) return;
    int beg = row_ptr[n];
    int end = (n + 1 < N_NODES) ? row_ptr[n + 1] : ET;
    float ad = AD[n];
    float den = 0.f;
    for (int p = beg + lane; p < end; p += 64)
        den += __expf(leaky(AS[esrc[p]] + ad));
    #pragma unroll
    for (int m = 32; m; m >>= 1) den += __shfl_xor(den, m);
    float r = 1.f / (den + 1e-16f);
    for (int p = beg + lane; p < end; p += 64)
        ALF2[p] = __expf(leaky(AS[esrc[p]] + ad)) * ewf[p] * r;
}

// ---- agg2: wave per node, precomputed alpha, writes d_out ----
__global__ __launch_bounds__(256) void agg2_csr_kernel(const int* __restrict__ row_ptr,
                                                       const int* __restrict__ esrc,
                                                       const float* __restrict__ ALF2,
                                                       const float* __restrict__ H2,
                                                       const float* __restrict__ b2,
                                                       float* __restrict__ OUT) {
    int lane = threadIdx.x & 63;
    int n = blockIdx.x * 4 + (threadIdx.x >> 6);
    if (n >= N_NODES) return;
    int beg = row_ptr[n];
    int end = (n + 1 < N_NODES) ? row_ptr[n + 1] : ET;
    float acc = 0.f;
    int p = beg;
    for (; p + 1 < end; p += 2) {
        int s0 = esrc[p], s1 = esrc[p + 1];
        float al0 = ALF2[p], al1 = ALF2[p + 1];
        if (lane < NCLS)
            acc += al0 * H2[(size_t)s0 * NCLS + lane] + al1 * H2[(size_t)s1 * NCLS + lane];
    }
    if (p < end) {
        int s0 = esrc[p];
        float al0 = ALF2[p];
        if (lane < NCLS) acc += al0 * H2[(size_t)s0 * NCLS + lane];
    }
    if (lane < NCLS)
        OUT[(size_t)n * NCLS + lane] = acc + b2[lane];
}

extern "C" void kernel_launch(void* const* d_in, const int* in_sizes, int n_in,
                              void* d_out, int out_size, void* d_ws, size_t ws_size,
                              hipStream_t stream) {
    const float* x    = (const float*)d_in[0];
    const int*   ei   = (const int*)d_in[1];
    const float* ew   = (const float*)d_in[2];
    const float* W1   = (const float*)d_in[3];
    const float* a_s1 = (const float*)d_in[4];
    const float* a_d1 = (const float*)d_in[5];
    const float* b1   = (const float*)d_in[6];
    const float* W2   = (const float*)d_in[7];
    const float* a_s2 = (const float*)d_in[8];
    const float* a_d2 = (const float*)d_in[9];
    const float* b2   = (const float*)d_in[10];
    float* out = (float*)d_out;

    // workspace:
    //  H1b[N*256 bf16] | OUT1b[N*256 bf16] | AS1[N*4] | AD1[N*4] | ALF1[ET float4]
    //  | row_ptr[N] | cnt[N] | fill[N] | esrc[ET] | ewf[ET] | sums | WT[256*512 bf16]
    //  layer2 (H2/AS2/AD2/ALF2, 11.8 MB) aliases into H1b region (25.6 MB, dead after agg1).
    unsigned short* H1b  = (unsigned short*)d_ws;
    unsigned short* OUT1b = H1b + (size_t)N_NODES * C1;
    float* AS1  = (float*)(OUT1b + (size_t)N_NODES * C1);
    float* AD1  = AS1 + N_NODES * HEADS;
    floatx4* ALF1 = (floatx4*)(AD1 + N_NODES * HEADS);
    int* row_ptr = (int*)(ALF1 + ET);
    int* cnt  = row_ptr + N_NODES;
    int* fill = cnt + N_NODES;
    int* esrc = fill + N_NODES;
    float* ewf = (float*)(esrc + ET);
    int* sums = (int*)(ewf + ET);
    unsigned short* WT = (unsigned short*)(sums + NCHUNK);
    float* H2   = (float*)H1b;             // alias
    float* AS2  = H2 + (size_t)N_NODES * NCLS;
    float* AD2  = AS2 + N_NODES;
    float* ALF2 = AD2 + N_NODES;

    // ---- CSR build + weight prep ----
    hipMemsetAsync(cnt, 0, N_NODES * sizeof(int), stream);
    wt_prep_kernel<<<dim3(F_IN / 32, C1 / 32), dim3(32, 8), 0, stream>>>(W1, WT);
    hist_kernel<<<(ET + 255) / 256, 256, 0, stream>>>(ei, cnt);
    chunk_sum_kernel<<<NCHUNK, 256, 0, stream>>>(cnt, sums);
    scan_sums_kernel<<<1, 64, 0, stream>>>(sums);
    rowptr_kernel<<<NCHUNK, 256, 0, stream>>>(cnt, sums, row_ptr, fill);
    scatter_kernel<<<(ET + 255) / 256, 256, 0, stream>>>(ei, ew, fill, esrc, ewf);

    // ---- layer 1 ----
    gemm1_mfma_kernel<<<(N_NODES + 127) / 128, 512, 0, stream>>>(x, WT, H1b);
    alphas1_kernel<<<(N_NODES * HEADS + 255) / 256, 256, 0, stream>>>(H1b, a_s1, a_d1, AS1, AD1);
    alpha1_prep_kernel<<<(N_NODES + 3) / 4, 256, 0, stream>>>(row_ptr, esrc, ewf, AS1, AD1, ALF1);
    agg1_csr_kernel<<<(N_NODES + 1) / 2, 256, 0, stream>>>(row_ptr, esrc, ALF1, H1b, b1, OUT1b);

    // ---- layer 2 ----
    gemm2_mfma_kernel<<<(N_NODES + 255) / 256, 512, 0, stream>>>(OUT1b, W2, H2);
    alphas2_kernel<<<(N_NODES + 255) / 256, 256, 0, stream>>>(H2, a_s2, a_d2, AS2, AD2);
    alpha2_prep_kernel<<<(N_NODES + 3) / 4, 256, 0, stream>>>(row_ptr, esrc, ewf, AS2, AD2, ALF2);
    agg2_csr_kernel<<<(N_NODES + 3) / 4, 256, 0, stream>>>(row_ptr, esrc, ALF2, H2, b2, out);
}

// Round 6
// 457.535 us; speedup vs baseline: 8.1452x; 1.1259x over previous
//
#include <hip/hip_runtime.h>
#include <math.h>

#define N_NODES 50000
#define N_EDGES 800000
#define ET (N_EDGES + N_NODES)   /* 850000 edges incl. self-loops */
#define F_IN 512
#define HID 64
#define HEADS 4
#define C1 (HEADS * HID)         /* 256 */
#define NCLS 40
#define NEG_SLOPE 0.2f
#define NCHUNK ((N_NODES + 255) / 256)   /* 196 */

typedef __attribute__((ext_vector_type(8))) short short8;
typedef __attribute__((ext_vector_type(4))) float floatx4;

__device__ __forceinline__ float leaky(float x) { return x >= 0.f ? x : NEG_SLOPE * x; }

// f32 -> bf16 round-to-nearest-even
__device__ __forceinline__ unsigned short f2bf(float f) {
    unsigned u = __float_as_uint(f);
    u += 0x7fffu + ((u >> 16) & 1u);
    return (unsigned short)(u >> 16);
}

__device__ __forceinline__ void edge_sd(int e, const int* __restrict__ ei,
                                        const float* __restrict__ ew,
                                        int& s, int& d, float& w) {
    if (e < N_EDGES) { s = ei[e]; d = ei[N_EDGES + e]; w = ew[e]; }
    else             { s = d = e - N_EDGES; w = 1.f; }
}

// ======================= CSR construction (per call) =======================
__global__ void hist_kernel(const int* __restrict__ ei, int* __restrict__ cnt) {
    int e = blockIdx.x * blockDim.x + threadIdx.x;
    if (e >= ET) return;
    int d = (e < N_EDGES) ? ei[N_EDGES + e] : e - N_EDGES;
    atomicAdd(&cnt[d], 1);
}

__global__ void chunk_sum_kernel(const int* __restrict__ cnt, int* __restrict__ sums) {
    __shared__ int sm[256];
    int i = blockIdx.x * 256 + threadIdx.x;
    sm[threadIdx.x] = (i < N_NODES) ? cnt[i] : 0;
    __syncthreads();
    for (int s = 128; s > 0; s >>= 1) {
        if (threadIdx.x < s) sm[threadIdx.x] += sm[threadIdx.x + s];
        __syncthreads();
    }
    if (threadIdx.x == 0) sums[blockIdx.x] = sm[0];
}

__global__ void scan_sums_kernel(int* __restrict__ sums) {
    if (threadIdx.x == 0) {
        int acc = 0;
        for (int i = 0; i < NCHUNK; i++) { int v = sums[i]; sums[i] = acc; acc += v; }
    }
}

__global__ void rowptr_kernel(const int* __restrict__ cnt, const int* __restrict__ sums,
                              int* __restrict__ row_ptr, int* __restrict__ fill) {
    __shared__ int sm[256];
    int i = blockIdx.x * 256 + threadIdx.x;
    int v = (i < N_NODES) ? cnt[i] : 0;
    sm[threadIdx.x] = v;
    __syncthreads();
    #pragma unroll
    for (int s = 1; s < 256; s <<= 1) {
        int t = (threadIdx.x >= s) ? sm[threadIdx.x - s] : 0;
        __syncthreads();
        sm[threadIdx.x] += t;
        __syncthreads();
    }
    int excl = sm[threadIdx.x] - v + sums[blockIdx.x];
    if (i < N_NODES) { row_ptr[i] = excl; fill[i] = excl; }
}

__global__ void scatter_kernel(const int* __restrict__ ei, const float* __restrict__ ew,
                               int* __restrict__ fill, int* __restrict__ esrc,
                               float* __restrict__ ewf) {
    int e = blockIdx.x * blockDim.x + threadIdx.x;
    if (e >= ET) return;
    int s, d; float w;
    edge_sd(e, ei, ew, s, d, w);
    int pos = atomicAdd(&fill[d], 1);
    esrc[pos] = s; ewf[pos] = w;
}

// ============ W1 -> bf16 transpose: WT[n][k] = bf16(W1[k][n]) ============
__global__ void wt_prep_kernel(const float* __restrict__ W, unsigned short* __restrict__ WT) {
    __shared__ float tile[32][33];
    int k0 = blockIdx.x * 32;
    int n0 = blockIdx.y * 32;
    int tx = threadIdx.x, ty = threadIdx.y;    // 32 x 8
    #pragma unroll
    for (int i = 0; i < 32; i += 8)
        tile[ty + i][tx] = W[(size_t)(k0 + ty + i) * C1 + n0 + tx];
    __syncthreads();
    #pragma unroll
    for (int i = 0; i < 32; i += 8)
        WT[(size_t)(n0 + ty + i) * F_IN + k0 + tx] = f2bf(tile[tx][ty + i]);
}

// ====== GEMM1 (bf16 MFMA): X[50000,512] @ W1[512,256] -> H1 (bf16) ======
__global__ __launch_bounds__(512) void gemm1_mfma_kernel(const float* __restrict__ X,
                                                         const unsigned short* __restrict__ WT,
                                                         unsigned short* __restrict__ H) {
    __shared__ short As[128][40];
    __shared__ short Bs[256][40];
    const int t = threadIdx.x;
    const int m0 = blockIdx.x * 128;
    const int lane = t & 63;
    const int wave = t >> 6;
    const int wm = wave >> 2;
    const int wn = wave & 3;
    const int l15 = lane & 15;
    const int quad = lane >> 4;

    const int ar = t >> 2;
    const int ac0 = (t & 3) * 8;
    const int gr = m0 + ar;
    const int bn = t >> 1;
    const int bc0 = (t & 1) * 16;

    floatx4 acc[4][4];
    #pragma unroll
    for (int i = 0; i < 4; i++)
        #pragma unroll
        for (int j = 0; j < 4; j++) acc[i][j] = (floatx4){0.f, 0.f, 0.f, 0.f};

    for (int k0 = 0; k0 < F_IN; k0 += 32) {
        float xv[8];
        if (gr < N_NODES) {
            const float4* p = (const float4*)(X + (size_t)gr * F_IN + k0 + ac0);
            float4 v0 = p[0], v1 = p[1];
            xv[0] = v0.x; xv[1] = v0.y; xv[2] = v0.z; xv[3] = v0.w;
            xv[4] = v1.x; xv[5] = v1.y; xv[6] = v1.z; xv[7] = v1.w;
        } else {
            #pragma unroll
            for (int i = 0; i < 8; i++) xv[i] = 0.f;
        }
        short8 av;
        #pragma unroll
        for (int i = 0; i < 8; i++) av[i] = (short)f2bf(xv[i]);
        *(short8*)&As[ar][ac0] = av;

        const short8* q = (const short8*)(WT + (size_t)bn * F_IN + k0 + bc0);
        *(short8*)&Bs[bn][bc0]     = q[0];
        *(short8*)&Bs[bn][bc0 + 8] = q[1];
        __syncthreads();

        short8 a[4], b[4];
        #pragma unroll
        for (int i = 0; i < 4; i++)
            a[i] = *(const short8*)&As[wm * 64 + i * 16 + l15][quad * 8];
        #pragma unroll
        for (int j = 0; j < 4; j++)
            b[j] = *(const short8*)&Bs[wn * 64 + j * 16 + l15][quad * 8];
        #pragma unroll
        for (int i = 0; i < 4; i++)
            #pragma unroll
            for (int j = 0; j < 4; j++)
                acc[i][j] = __builtin_amdgcn_mfma_f32_16x16x32_bf16(a[i], b[j], acc[i][j], 0, 0, 0);
        __syncthreads();
    }

    #pragma unroll
    for (int i = 0; i < 4; i++) {
        int rbase = m0 + wm * 64 + i * 16 + quad * 4;
        #pragma unroll
        for (int j = 0; j < 4; j++) {
            int col = wn * 64 + j * 16 + l15;
            #pragma unroll
            for (int r = 0; r < 4; r++) {
                int row = rbase + r;
                if (row < N_NODES) H[(size_t)row * C1 + col] = f2bf(acc[i][j][r]);
            }
        }
    }
}

// -------- per-(node,head) attention logits (bf16 H) --------
__global__ void alphas1_kernel(const unsigned short* __restrict__ H,
                               const float* __restrict__ a_src,
                               const float* __restrict__ a_dst,
                               float* __restrict__ AS, float* __restrict__ AD) {
    int t = blockIdx.x * blockDim.x + threadIdx.x;
    if (t >= N_NODES * HEADS) return;
    int n = t >> 2, h = t & 3;
    const unsigned* hp = (const unsigned*)(H + (size_t)n * C1 + h * HID);
    const float* sp = a_src + h * HID;
    const float* dp = a_dst + h * HID;
    float s = 0.f, d = 0.f;
    #pragma unroll 8
    for (int k = 0; k < HID / 2; k++) {
        unsigned u = hp[k];
        float v0 = __uint_as_float(u << 16);
        float v1 = __uint_as_float(u & 0xffff0000u);
        s += v0 * sp[2 * k] + v1 * sp[2 * k + 1];
        d += v0 * dp[2 * k] + v1 * dp[2 * k + 1];
    }
    AS[t] = s; AD[t] = d;
}

// ---- per-edge normalized alpha (4 heads), CSR order; wave per node ----
__global__ __launch_bounds__(256) void alpha1_prep_kernel(const int* __restrict__ row_ptr,
                                                          const int* __restrict__ esrc,
                                                          const float* __restrict__ ewf,
                                                          const float* __restrict__ AS,
                                                          const float* __restrict__ AD,
                                                          floatx4* __restrict__ ALF) {
    int lane = threadIdx.x & 63;
    int n = blockIdx.x * 4 + (threadIdx.x >> 6);
    if (n >= N_NODES) return;
    int beg = row_ptr[n];
    int end = (n + 1 < N_NODES) ? row_ptr[n + 1] : ET;
    const float4 ad = *(const float4*)(AD + n * 4);
    float dx = 0.f, dy = 0.f, dz = 0.f, dw = 0.f;
    for (int p = beg + lane; p < end; p += 64) {
        const float4 as = *(const float4*)(AS + esrc[p] * 4);
        dx += __expf(leaky(as.x + ad.x));
        dy += __expf(leaky(as.y + ad.y));
        dz += __expf(leaky(as.z + ad.z));
        dw += __expf(leaky(as.w + ad.w));
    }
    #pragma unroll
    for (int m = 32; m; m >>= 1) {
        dx += __shfl_xor(dx, m); dy += __shfl_xor(dy, m);
        dz += __shfl_xor(dz, m); dw += __shfl_xor(dw, m);
    }
    float rx = 1.f / (dx + 1e-16f), ry = 1.f / (dy + 1e-16f);
    float rz = 1.f / (dz + 1e-16f), rw = 1.f / (dw + 1e-16f);
    for (int p = beg + lane; p < end; p += 64) {
        const float4 as = *(const float4*)(AS + esrc[p] * 4);
        float w = ewf[p];
        floatx4 a;
        a[0] = __expf(leaky(as.x + ad.x)) * w * rx;
        a[1] = __expf(leaky(as.y + ad.y)) * w * ry;
        a[2] = __expf(leaky(as.z + ad.z)) * w * rz;
        a[3] = __expf(leaky(as.w + ad.w)) * w * rw;
        ALF[p] = a;
    }
}

// ---- agg1 v2: wave per node (4/block), 4 ch/thread (8B loads), 4-edge unroll.
//      All 4 H-gathers per group are independent -> MLP 4; esrc/alpha loads are
//      address-independent of the gathers and prefetchable by the scheduler. ----
__global__ __launch_bounds__(256) void agg1_csr_kernel(const int* __restrict__ row_ptr,
                                                       const int* __restrict__ esrc,
                                                       const float* __restrict__ ALF,
                                                       const unsigned short* __restrict__ H,
                                                       const float* __restrict__ b1,
                                                       unsigned short* __restrict__ OUT) {
    int n = blockIdx.x * 4 + (threadIdx.x >> 6);
    int lane = threadIdx.x & 63;
    if (n >= N_NODES) return;
    int c0 = lane * 4;                  // 4 channels per thread
    int h = lane >> 4;                  // head
    int beg = row_ptr[n];
    int end = (n + 1 < N_NODES) ? row_ptr[n + 1] : ET;
    float a0 = 0.f, a1 = 0.f, a2 = 0.f, a3 = 0.f;
    int p = beg;
    for (; p + 4 <= end; p += 4) {
        int s0 = esrc[p], s1 = esrc[p + 1], s2 = esrc[p + 2], s3 = esrc[p + 3];
        float al0 = ALF[(size_t)(p    ) * 4 + h];
        float al1 = ALF[(size_t)(p + 1) * 4 + h];
        float al2 = ALF[(size_t)(p + 2) * 4 + h];
        float al3 = ALF[(size_t)(p + 3) * 4 + h];
        uint2 u0 = *(const uint2*)(H + (size_t)s0 * C1 + c0);
        uint2 u1 = *(const uint2*)(H + (size_t)s1 * C1 + c0);
        uint2 u2 = *(const uint2*)(H + (size_t)s2 * C1 + c0);
        uint2 u3 = *(const uint2*)(H + (size_t)s3 * C1 + c0);
        a0 += al0 * __uint_as_float(u0.x << 16)        + al1 * __uint_as_float(u1.x << 16)
            + al2 * __uint_as_float(u2.x << 16)        + al3 * __uint_as_float(u3.x << 16);
        a1 += al0 * __uint_as_float(u0.x & 0xffff0000u) + al1 * __uint_as_float(u1.x & 0xffff0000u)
            + al2 * __uint_as_float(u2.x & 0xffff0000u) + al3 * __uint_as_float(u3.x & 0xffff0000u);
        a2 += al0 * __uint_as_float(u0.y << 16)        + al1 * __uint_as_float(u1.y << 16)
            + al2 * __uint_as_float(u2.y << 16)        + al3 * __uint_as_float(u3.y << 16);
        a3 += al0 * __uint_as_float(u0.y & 0xffff0000u) + al1 * __uint_as_float(u1.y & 0xffff0000u)
            + al2 * __uint_as_float(u2.y & 0xffff0000u) + al3 * __uint_as_float(u3.y & 0xffff0000u);
    }
    for (; p < end; p++) {
        int s0 = esrc[p];
        float al0 = ALF[(size_t)p * 4 + h];
        uint2 u0 = *(const uint2*)(H + (size_t)s0 * C1 + c0);
        a0 += al0 * __uint_as_float(u0.x << 16);
        a1 += al0 * __uint_as_float(u0.x & 0xffff0000u);
        a2 += al0 * __uint_as_float(u0.y << 16);
        a3 += al0 * __uint_as_float(u0.y & 0xffff0000u);
    }
    float4 bv = *(const float4*)(b1 + c0);
    float v0 = a0 + bv.x, v1 = a1 + bv.y, v2 = a2 + bv.z, v3 = a3 + bv.w;
    v0 = v0 > 0.f ? v0 : 0.f;
    v1 = v1 > 0.f ? v1 : 0.f;
    v2 = v2 > 0.f ? v2 : 0.f;
    v3 = v3 > 0.f ? v3 : 0.f;
    uint2 o;
    o.x = ((unsigned)f2bf(v1) << 16) | (unsigned)f2bf(v0);
    o.y = ((unsigned)f2bf(v3) << 16) | (unsigned)f2bf(v2);
    *(uint2*)(OUT + (size_t)n * C1 + c0) = o;
}

// ====== GEMM2 (bf16 MFMA): OUT1b[50000,256] @ W2[256,40] -> H2 (f32) ======
#define BROW 264   /* LDS row stride for Bs2: 528B = 33*16, 16B-aligned */
__global__ __launch_bounds__(512) void gemm2_mfma_kernel(const unsigned short* __restrict__ A,
                                                         const float* __restrict__ W2,
                                                         float* __restrict__ H2) {
    __shared__ short As[256][40];        // 20 KB
    __shared__ short Bs[48 * BROW];      // 25.3 KB
    const int t = threadIdx.x;
    const int m0 = blockIdx.x * 256;
    const int lane = t & 63;
    const int wave = t >> 6;
    const int l15 = lane & 15;
    const int quad = lane >> 4;

    for (int i = t; i < 48 * 256; i += 512) {
        int n = i >> 8, k = i & 255;
        float v = (n < NCLS) ? W2[k * NCLS + n] : 0.f;
        Bs[n * BROW + k] = (short)f2bf(v);
    }

    const int ar = t >> 1;
    const int ac0 = (t & 1) * 16;

    floatx4 acc[2][3];
    #pragma unroll
    for (int i = 0; i < 2; i++)
        #pragma unroll
        for (int j = 0; j < 3; j++) acc[i][j] = (floatx4){0.f, 0.f, 0.f, 0.f};

    for (int k0 = 0; k0 < C1; k0 += 32) {
        const short8* q = (const short8*)(A + (size_t)(m0 + ar) * C1 + k0 + ac0);
        short8 v0 = q[0], v1 = q[1];
        __syncthreads();
        *(short8*)&As[ar][ac0]     = v0;
        *(short8*)&As[ar][ac0 + 8] = v1;
        __syncthreads();

        short8 a[2], b[3];
        #pragma unroll
        for (int i = 0; i < 2; i++)
            a[i] = *(const short8*)&As[wave * 32 + i * 16 + l15][quad * 8];
        #pragma unroll
        for (int j = 0; j < 3; j++)
            b[j] = *(const short8*)&Bs[(j * 16 + l15) * BROW + k0 + quad * 8];
        #pragma unroll
        for (int i = 0; i < 2; i++)
            #pragma unroll
            for (int j = 0; j < 3; j++)
                acc[i][j] = __builtin_amdgcn_mfma_f32_16x16x32_bf16(a[i], b[j], acc[i][j], 0, 0, 0);
    }

    #pragma unroll
    for (int i = 0; i < 2; i++) {
        int rbase = m0 + wave * 32 + i * 16 + quad * 4;
        #pragma unroll
        for (int j = 0; j < 3; j++) {
            int col = j * 16 + l15;
            if (col < NCLS) {
                #pragma unroll
                for (int r = 0; r < 4; r++) {
                    int row = rbase + r;
                    if (row < N_NODES) H2[(size_t)row * NCLS + col] = acc[i][j][r];
                }
            }
        }
    }
}

__global__ void alphas2_kernel(const float* __restrict__ H2, const float* __restrict__ a_src,
                               const float* __restrict__ a_dst, float* __restrict__ AS,
                               float* __restrict__ AD) {
    int n = blockIdx.x * blockDim.x + threadIdx.x;
    if (n >= N_NODES) return;
    float s = 0.f, d = 0.f;
    #pragma unroll
    for (int k = 0; k < NCLS; k++) {
        float v = H2[(size_t)n * NCLS + k];
        s += v * a_src[k]; d += v * a_dst[k];
    }
    AS[n] = s; AD[n] = d;
}

// ---- per-edge normalized alpha layer2 ----
__global__ __launch_bounds__(256) void alpha2_prep_kernel(const int* __restrict__ row_ptr,
                                                          const int* __restrict__ esrc,
                                                          const float* __restrict__ ewf,
                                                          const float* __restrict__ AS,
                                                          const float* __restrict__ AD,
                                                          float* __restrict__ ALF2) {
    int lane = threadIdx.x & 63;
    int n = blockIdx.x * 4 + (threadIdx.x >> 6);
    if (n >= N_NODES) return;
    int beg = row_ptr[n];
    int end = (n + 1 < N_NODES) ? row_ptr[n + 1] : ET;
    float ad = AD[n];
    float den = 0.f;
    for (int p = beg + lane; p < end; p += 64)
        den += __expf(leaky(AS[esrc[p]] + ad));
    #pragma unroll
    for (int m = 32; m; m >>= 1) den += __shfl_xor(den, m);
    float r = 1.f / (den + 1e-16f);
    for (int p = beg + lane; p < end; p += 64)
        ALF2[p] = __expf(leaky(AS[esrc[p]] + ad)) * ewf[p] * r;
}

// ---- agg2: wave per node, precomputed alpha, 4-edge unroll, writes d_out ----
__global__ __launch_bounds__(256) void agg2_csr_kernel(const int* __restrict__ row_ptr,
                                                       const int* __restrict__ esrc,
                                                       const float* __restrict__ ALF2,
                                                       const float* __restrict__ H2,
                                                       const float* __restrict__ b2,
                                                       float* __restrict__ OUT) {
    int lane = threadIdx.x & 63;
    int n = blockIdx.x * 4 + (threadIdx.x >> 6);
    if (n >= N_NODES) return;
    int beg = row_ptr[n];
    int end = (n + 1 < N_NODES) ? row_ptr[n + 1] : ET;
    float acc = 0.f;
    int p = beg;
    bool act = lane < NCLS;
    for (; p + 4 <= end; p += 4) {
        int s0 = esrc[p], s1 = esrc[p + 1], s2 = esrc[p + 2], s3 = esrc[p + 3];
        float al0 = ALF2[p], al1 = ALF2[p + 1], al2 = ALF2[p + 2], al3 = ALF2[p + 3];
        if (act) {
            float h0 = H2[(size_t)s0 * NCLS + lane];
            float h1 = H2[(size_t)s1 * NCLS + lane];
            float h2 = H2[(size_t)s2 * NCLS + lane];
            float h3 = H2[(size_t)s3 * NCLS + lane];
            acc += al0 * h0 + al1 * h1 + al2 * h2 + al3 * h3;
        }
    }
    for (; p < end; p++) {
        int s0 = esrc[p];
        float al0 = ALF2[p];
        if (act) acc += al0 * H2[(size_t)s0 * NCLS + lane];
    }
    if (act)
        OUT[(size_t)n * NCLS + lane] = acc + b2[lane];
}

extern "C" void kernel_launch(void* const* d_in, const int* in_sizes, int n_in,
                              void* d_out, int out_size, void* d_ws, size_t ws_size,
                              hipStream_t stream) {
    const float* x    = (const float*)d_in[0];
    const int*   ei   = (const int*)d_in[1];
    const float* ew   = (const float*)d_in[2];
    const float* W1   = (const float*)d_in[3];
    const float* a_s1 = (const float*)d_in[4];
    const float* a_d1 = (const float*)d_in[5];
    const float* b1   = (const float*)d_in[6];
    const float* W2   = (const float*)d_in[7];
    const float* a_s2 = (const float*)d_in[8];
    const float* a_d2 = (const float*)d_in[9];
    const float* b2   = (const float*)d_in[10];
    float* out = (float*)d_out;

    unsigned short* H1b  = (unsigned short*)d_ws;
    unsigned short* OUT1b = H1b + (size_t)N_NODES * C1;
    float* AS1  = (float*)(OUT1b + (size_t)N_NODES * C1);
    float* AD1  = AS1 + N_NODES * HEADS;
    floatx4* ALF1 = (floatx4*)(AD1 + N_NODES * HEADS);
    int* row_ptr = (int*)(ALF1 + ET);
    int* cnt  = row_ptr + N_NODES;
    int* fill = cnt + N_NODES;
    int* esrc = fill + N_NODES;
    float* ewf = (float*)(esrc + ET);
    int* sums = (int*)(ewf + ET);
    unsigned short* WT = (unsigned short*)(sums + NCHUNK);
    float* H2   = (float*)H1b;             // alias (H1b dead before gemm2 writes)
    float* AS2  = H2 + (size_t)N_NODES * NCLS;
    float* AD2  = AS2 + N_NODES;
    float* ALF2 = AD2 + N_NODES;

    // ---- CSR build + weight prep ----
    hipMemsetAsync(cnt, 0, N_NODES * sizeof(int), stream);
    wt_prep_kernel<<<dim3(F_IN / 32, C1 / 32), dim3(32, 8), 0, stream>>>(W1, WT);
    hist_kernel<<<(ET + 255) / 256, 256, 0, stream>>>(ei, cnt);
    chunk_sum_kernel<<<NCHUNK, 256, 0, stream>>>(cnt, sums);
    scan_sums_kernel<<<1, 64, 0, stream>>>(sums);
    rowptr_kernel<<<NCHUNK, 256, 0, stream>>>(cnt, sums, row_ptr, fill);
    scatter_kernel<<<(ET + 255) / 256, 256, 0, stream>>>(ei, ew, fill, esrc, ewf);

    // ---- layer 1 ----
    gemm1_mfma_kernel<<<(N_NODES + 127) / 128, 512, 0, stream>>>(x, WT, H1b);
    alphas1_kernel<<<(N_NODES * HEADS + 255) / 256, 256, 0, stream>>>(H1b, a_s1, a_d1, AS1, AD1);
    alpha1_prep_kernel<<<(N_NODES + 3) / 4, 256, 0, stream>>>(row_ptr, esrc, ewf, AS1, AD1, ALF1);
    agg1_csr_kernel<<<(N_NODES + 3) / 4, 256, 0, stream>>>(row_ptr, esrc, (const float*)ALF1, H1b, b1, OUT1b);

    // ---- layer 2 ----
    gemm2_mfma_kernel<<<(N_NODES + 255) / 256, 512, 0, stream>>>(OUT1b, W2, H2);
    alphas2_kernel<<<(N_NODES + 255) / 256, 256, 0, stream>>>(H2, a_s2, a_d2, AS2, AD2);
    alpha2_prep_kernel<<<(N_NODES + 3) / 4, 256, 0, stream>>>(row_ptr, esrc, ewf, AS2, AD2, ALF2);
    agg2_csr_kernel<<<(N_NODES + 3) / 4, 256, 0, stream>>>(row_ptr, esrc, ALF2, H2, b2, out);
}

// Round 7
// 437.300 us; speedup vs baseline: 8.5221x; 1.0463x over previous
//
#include <hip/hip_runtime.h>
#include <math.h>

#define N_NODES 50000
#define N_EDGES 800000
#define ET (N_EDGES + N_NODES)   /* 850000 edges incl. self-loops */
#define F_IN 512
#define HID 64
#define HEADS 4
#define C1 (HEADS * HID)         /* 256 */
#define NCLS 40
#define NEG_SLOPE 0.2f
#define NCHUNK ((N_NODES + 255) / 256)   /* 196 */

typedef __attribute__((ext_vector_type(8))) short short8;
typedef __attribute__((ext_vector_type(4))) float floatx4;

__device__ __forceinline__ float leaky(float x) { return x >= 0.f ? x : NEG_SLOPE * x; }

// f32 -> bf16 round-to-nearest-even
__device__ __forceinline__ unsigned short f2bf(float f) {
    unsigned u = __float_as_uint(f);
    u += 0x7fffu + ((u >> 16) & 1u);
    return (unsigned short)(u >> 16);
}
__device__ __forceinline__ float bf2f(unsigned short u) {
    return __uint_as_float(((unsigned)u) << 16);
}

__device__ __forceinline__ void edge_sd(int e, const int* __restrict__ ei,
                                        const float* __restrict__ ew,
                                        int& s, int& d, float& w) {
    if (e < N_EDGES) { s = ei[e]; d = ei[N_EDGES + e]; w = ew[e]; }
    else             { s = d = e - N_EDGES; w = 1.f; }
}

// ======================= CSR construction (per call) =======================
__global__ void hist_kernel(const int* __restrict__ ei, int* __restrict__ cnt) {
    int e = blockIdx.x * blockDim.x + threadIdx.x;
    if (e >= ET) return;
    int d = (e < N_EDGES) ? ei[N_EDGES + e] : e - N_EDGES;
    atomicAdd(&cnt[d], 1);
}

__global__ void chunk_sum_kernel(const int* __restrict__ cnt, int* __restrict__ sums) {
    __shared__ int sm[256];
    int i = blockIdx.x * 256 + threadIdx.x;
    sm[threadIdx.x] = (i < N_NODES) ? cnt[i] : 0;
    __syncthreads();
    for (int s = 128; s > 0; s >>= 1) {
        if (threadIdx.x < s) sm[threadIdx.x] += sm[threadIdx.x + s];
        __syncthreads();
    }
    if (threadIdx.x == 0) sums[blockIdx.x] = sm[0];
}

// parallel single-block exclusive scan of the 196 chunk sums (was a serial
// 196-dependent-load loop ~25us; now ~2us)
__global__ void scan_sums_kernel(int* __restrict__ sums) {
    __shared__ int sm[256];
    int i = threadIdx.x;
    int v = (i < NCHUNK) ? sums[i] : 0;
    sm[i] = v;
    __syncthreads();
    #pragma unroll
    for (int s = 1; s < 256; s <<= 1) {
        int t = (i >= s) ? sm[i - s] : 0;
        __syncthreads();
        sm[i] += t;
        __syncthreads();
    }
    if (i < NCHUNK) sums[i] = sm[i] - v;   // exclusive
}

__global__ void rowptr_kernel(const int* __restrict__ cnt, const int* __restrict__ sums,
                              int* __restrict__ row_ptr, int* __restrict__ fill) {
    __shared__ int sm[256];
    int i = blockIdx.x * 256 + threadIdx.x;
    int v = (i < N_NODES) ? cnt[i] : 0;
    sm[threadIdx.x] = v;
    __syncthreads();
    #pragma unroll
    for (int s = 1; s < 256; s <<= 1) {
        int t = (threadIdx.x >= s) ? sm[threadIdx.x - s] : 0;
        __syncthreads();
        sm[threadIdx.x] += t;
        __syncthreads();
    }
    int excl = sm[threadIdx.x] - v + sums[blockIdx.x];
    if (i < N_NODES) { row_ptr[i] = excl; fill[i] = excl; }
}

// CSR payload: (src, edge_weight) packed in one int2 per edge
__global__ void scatter_kernel(const int* __restrict__ ei, const float* __restrict__ ew,
                               int* __restrict__ fill, int2* __restrict__ E2) {
    int e = blockIdx.x * blockDim.x + threadIdx.x;
    if (e >= ET) return;
    int s, d; float w;
    edge_sd(e, ei, ew, s, d, w);
    int pos = atomicAdd(&fill[d], 1);
    E2[pos] = make_int2(s, __float_as_int(w));
}

// ============ W1 -> bf16 transpose: WT[n][k] = bf16(W1[k][n]) ============
__global__ void wt_prep_kernel(const float* __restrict__ W, unsigned short* __restrict__ WT) {
    __shared__ float tile[32][33];
    int k0 = blockIdx.x * 32;
    int n0 = blockIdx.y * 32;
    int tx = threadIdx.x, ty = threadIdx.y;    // 32 x 8
    #pragma unroll
    for (int i = 0; i < 32; i += 8)
        tile[ty + i][tx] = W[(size_t)(k0 + ty + i) * C1 + n0 + tx];
    __syncthreads();
    #pragma unroll
    for (int i = 0; i < 32; i += 8)
        WT[(size_t)(n0 + ty + i) * F_IN + k0 + tx] = f2bf(tile[tx][ty + i]);
}

// ====== GEMM1 (bf16 MFMA): X[50000,512] @ W1[512,256] -> H1 (bf16) ======
__global__ __launch_bounds__(512) void gemm1_mfma_kernel(const float* __restrict__ X,
                                                         const unsigned short* __restrict__ WT,
                                                         unsigned short* __restrict__ H) {
    __shared__ short As[128][40];
    __shared__ short Bs[256][40];
    const int t = threadIdx.x;
    const int m0 = blockIdx.x * 128;
    const int lane = t & 63;
    const int wave = t >> 6;
    const int wm = wave >> 2;
    const int wn = wave & 3;
    const int l15 = lane & 15;
    const int quad = lane >> 4;

    const int ar = t >> 2;
    const int ac0 = (t & 3) * 8;
    const int gr = m0 + ar;
    const int bn = t >> 1;
    const int bc0 = (t & 1) * 16;

    floatx4 acc[4][4];
    #pragma unroll
    for (int i = 0; i < 4; i++)
        #pragma unroll
        for (int j = 0; j < 4; j++) acc[i][j] = (floatx4){0.f, 0.f, 0.f, 0.f};

    for (int k0 = 0; k0 < F_IN; k0 += 32) {
        float xv[8];
        if (gr < N_NODES) {
            const float4* p = (const float4*)(X + (size_t)gr * F_IN + k0 + ac0);
            float4 v0 = p[0], v1 = p[1];
            xv[0] = v0.x; xv[1] = v0.y; xv[2] = v0.z; xv[3] = v0.w;
            xv[4] = v1.x; xv[5] = v1.y; xv[6] = v1.z; xv[7] = v1.w;
        } else {
            #pragma unroll
            for (int i = 0; i < 8; i++) xv[i] = 0.f;
        }
        short8 av;
        #pragma unroll
        for (int i = 0; i < 8; i++) av[i] = (short)f2bf(xv[i]);
        *(short8*)&As[ar][ac0] = av;

        const short8* q = (const short8*)(WT + (size_t)bn * F_IN + k0 + bc0);
        *(short8*)&Bs[bn][bc0]     = q[0];
        *(short8*)&Bs[bn][bc0 + 8] = q[1];
        __syncthreads();

        short8 a[4], b[4];
        #pragma unroll
        for (int i = 0; i < 4; i++)
            a[i] = *(const short8*)&As[wm * 64 + i * 16 + l15][quad * 8];
        #pragma unroll
        for (int j = 0; j < 4; j++)
            b[j] = *(const short8*)&Bs[wn * 64 + j * 16 + l15][quad * 8];
        #pragma unroll
        for (int i = 0; i < 4; i++)
            #pragma unroll
            for (int j = 0; j < 4; j++)
                acc[i][j] = __builtin_amdgcn_mfma_f32_16x16x32_bf16(a[i], b[j], acc[i][j], 0, 0, 0);
        __syncthreads();
    }

    #pragma unroll
    for (int i = 0; i < 4; i++) {
        int rbase = m0 + wm * 64 + i * 16 + quad * 4;
        #pragma unroll
        for (int j = 0; j < 4; j++) {
            int col = wn * 64 + j * 16 + l15;
            #pragma unroll
            for (int r = 0; r < 4; r++) {
                int row = rbase + r;
                if (row < N_NODES) H[(size_t)row * C1 + col] = f2bf(acc[i][j][r]);
            }
        }
    }
}

// -------- per-(node,head) attention logits (bf16 H) --------
__global__ void alphas1_kernel(const unsigned short* __restrict__ H,
                               const float* __restrict__ a_src,
                               const float* __restrict__ a_dst,
                               float* __restrict__ AS, float* __restrict__ AD) {
    int t = blockIdx.x * blockDim.x + threadIdx.x;
    if (t >= N_NODES * HEADS) return;
    int n = t >> 2, h = t & 3;
    const unsigned* hp = (const unsigned*)(H + (size_t)n * C1 + h * HID);
    const float* sp = a_src + h * HID;
    const float* dp = a_dst + h * HID;
    float s = 0.f, d = 0.f;
    #pragma unroll 8
    for (int k = 0; k < HID / 2; k++) {
        unsigned u = hp[k];
        float v0 = __uint_as_float(u << 16);
        float v1 = __uint_as_float(u & 0xffff0000u);
        s += v0 * sp[2 * k] + v1 * sp[2 * k + 1];
        d += v0 * dp[2 * k] + v1 * dp[2 * k + 1];
    }
    AS[t] = s; AD[t] = d;
}

// ---- agg1 v3: wave per node, 4 ch/thread, 4-edge unroll, INLINE softmax.
//      Each lane sees all edges of its node -> accumulates its own denominator
//      (redundant across lanes, but v_exp is cheap and AS1 is L2-resident).
//      Normalize once at the end: OUT = (sum pe*w*h)/(sum pe). ----
__global__ __launch_bounds__(256) void agg1_csr_kernel(const int* __restrict__ row_ptr,
                                                       const int2* __restrict__ E2,
                                                       const float* __restrict__ AS,
                                                       const float* __restrict__ AD,
                                                       const unsigned short* __restrict__ H,
                                                       const float* __restrict__ b1,
                                                       unsigned short* __restrict__ OUT) {
    int n = blockIdx.x * 4 + (threadIdx.x >> 6);
    int lane = threadIdx.x & 63;
    if (n >= N_NODES) return;
    int c0 = lane * 4;                  // 4 channels per thread
    int h = lane >> 4;                  // head
    int beg = row_ptr[n];
    int end = (n + 1 < N_NODES) ? row_ptr[n + 1] : ET;
    float ad = AD[n * 4 + h];
    float den = 0.f;
    float a0 = 0.f, a1 = 0.f, a2 = 0.f, a3 = 0.f;
    int p = beg;
    for (; p + 4 <= end; p += 4) {
        int2 e0 = E2[p], e1 = E2[p + 1], e2 = E2[p + 2], e3 = E2[p + 3];
        float pe0 = __expf(leaky(AS[e0.x * 4 + h] + ad));
        float pe1 = __expf(leaky(AS[e1.x * 4 + h] + ad));
        float pe2 = __expf(leaky(AS[e2.x * 4 + h] + ad));
        float pe3 = __expf(leaky(AS[e3.x * 4 + h] + ad));
        den += pe0 + pe1 + pe2 + pe3;
        float pw0 = pe0 * __int_as_float(e0.y);
        float pw1 = pe1 * __int_as_float(e1.y);
        float pw2 = pe2 * __int_as_float(e2.y);
        float pw3 = pe3 * __int_as_float(e3.y);
        uint2 u0 = *(const uint2*)(H + (size_t)e0.x * C1 + c0);
        uint2 u1 = *(const uint2*)(H + (size_t)e1.x * C1 + c0);
        uint2 u2 = *(const uint2*)(H + (size_t)e2.x * C1 + c0);
        uint2 u3 = *(const uint2*)(H + (size_t)e3.x * C1 + c0);
        a0 += pw0 * __uint_as_float(u0.x << 16)         + pw1 * __uint_as_float(u1.x << 16)
            + pw2 * __uint_as_float(u2.x << 16)         + pw3 * __uint_as_float(u3.x << 16);
        a1 += pw0 * __uint_as_float(u0.x & 0xffff0000u) + pw1 * __uint_as_float(u1.x & 0xffff0000u)
            + pw2 * __uint_as_float(u2.x & 0xffff0000u) + pw3 * __uint_as_float(u3.x & 0xffff0000u);
        a2 += pw0 * __uint_as_float(u0.y << 16)         + pw1 * __uint_as_float(u1.y << 16)
            + pw2 * __uint_as_float(u2.y << 16)         + pw3 * __uint_as_float(u3.y << 16);
        a3 += pw0 * __uint_as_float(u0.y & 0xffff0000u) + pw1 * __uint_as_float(u1.y & 0xffff0000u)
            + pw2 * __uint_as_float(u2.y & 0xffff0000u) + pw3 * __uint_as_float(u3.y & 0xffff0000u);
    }
    for (; p < end; p++) {
        int2 e0 = E2[p];
        float pe0 = __expf(leaky(AS[e0.x * 4 + h] + ad));
        den += pe0;
        float pw0 = pe0 * __int_as_float(e0.y);
        uint2 u0 = *(const uint2*)(H + (size_t)e0.x * C1 + c0);
        a0 += pw0 * __uint_as_float(u0.x << 16);
        a1 += pw0 * __uint_as_float(u0.x & 0xffff0000u);
        a2 += pw0 * __uint_as_float(u0.y << 16);
        a3 += pw0 * __uint_as_float(u0.y & 0xffff0000u);
    }
    float r = 1.f / (den + 1e-16f);
    float4 bv = *(const float4*)(b1 + c0);
    float v0 = a0 * r + bv.x, v1 = a1 * r + bv.y, v2 = a2 * r + bv.z, v3 = a3 * r + bv.w;
    v0 = v0 > 0.f ? v0 : 0.f;
    v1 = v1 > 0.f ? v1 : 0.f;
    v2 = v2 > 0.f ? v2 : 0.f;
    v3 = v3 > 0.f ? v3 : 0.f;
    uint2 o;
    o.x = ((unsigned)f2bf(v1) << 16) | (unsigned)f2bf(v0);
    o.y = ((unsigned)f2bf(v3) << 16) | (unsigned)f2bf(v2);
    *(uint2*)(OUT + (size_t)n * C1 + c0) = o;
}

// ====== GEMM2 (bf16 MFMA) + fused alphas2: OUT1b @ W2 -> H2b (bf16), AS2/AD2 ======
// Each wave holds full 48-col rows -> per-row logits via 16-lane shuffle reduce.
#define BROW 264   /* LDS row stride for Bs2: 528B, 16B-aligned */
__global__ __launch_bounds__(512) void gemm2_mfma_kernel(const unsigned short* __restrict__ A,
                                                         const float* __restrict__ W2,
                                                         const float* __restrict__ a_s2,
                                                         const float* __restrict__ a_d2,
                                                         unsigned short* __restrict__ H2b,
                                                         float* __restrict__ AS2,
                                                         float* __restrict__ AD2) {
    __shared__ short As[256][40];        // 20 KB
    __shared__ short Bs[48 * BROW];      // 25.3 KB
    const int t = threadIdx.x;
    const int m0 = blockIdx.x * 256;
    const int lane = t & 63;
    const int wave = t >> 6;
    const int l15 = lane & 15;
    const int quad = lane >> 4;

    for (int i = t; i < 48 * 256; i += 512) {
        int n = i >> 8, k = i & 255;
        float v = (n < NCLS) ? W2[k * NCLS + n] : 0.f;
        Bs[n * BROW + k] = (short)f2bf(v);
    }

    const int ar = t >> 1;
    const int ac0 = (t & 1) * 16;

    floatx4 acc[2][3];
    #pragma unroll
    for (int i = 0; i < 2; i++)
        #pragma unroll
        for (int j = 0; j < 3; j++) acc[i][j] = (floatx4){0.f, 0.f, 0.f, 0.f};

    for (int k0 = 0; k0 < C1; k0 += 32) {
        const short8* q = (const short8*)(A + (size_t)(m0 + ar) * C1 + k0 + ac0);
        short8 v0 = q[0], v1 = q[1];
        __syncthreads();
        *(short8*)&As[ar][ac0]     = v0;
        *(short8*)&As[ar][ac0 + 8] = v1;
        __syncthreads();

        short8 a[2], b[3];
        #pragma unroll
        for (int i = 0; i < 2; i++)
            a[i] = *(const short8*)&As[wave * 32 + i * 16 + l15][quad * 8];
        #pragma unroll
        for (int j = 0; j < 3; j++)
            b[j] = *(const short8*)&Bs[(j * 16 + l15) * BROW + k0 + quad * 8];
        #pragma unroll
        for (int i = 0; i < 2; i++)
            #pragma unroll
            for (int j = 0; j < 3; j++)
                acc[i][j] = __builtin_amdgcn_mfma_f32_16x16x32_bf16(a[i], b[j], acc[i][j], 0, 0, 0);
    }

    // per-lane attention-vector slices
    float asr[3], adr[3];
    #pragma unroll
    for (int j = 0; j < 3; j++) {
        int col = j * 16 + l15;
        asr[j] = (col < NCLS) ? a_s2[col] : 0.f;
        adr[j] = (col < NCLS) ? a_d2[col] : 0.f;
    }

    #pragma unroll
    for (int i = 0; i < 2; i++) {
        #pragma unroll
        for (int r = 0; r < 4; r++) {
            int row = m0 + wave * 32 + i * 16 + quad * 4 + r;
            float s_ = acc[i][0][r] * asr[0] + acc[i][1][r] * asr[1] + acc[i][2][r] * asr[2];
            float d_ = acc[i][0][r] * adr[0] + acc[i][1][r] * adr[1] + acc[i][2][r] * adr[2];
            #pragma unroll
            for (int m = 8; m; m >>= 1) { s_ += __shfl_xor(s_, m); d_ += __shfl_xor(d_, m); }
            if (l15 == 0 && row < N_NODES) { AS2[row] = s_; AD2[row] = d_; }
            #pragma unroll
            for (int j = 0; j < 3; j++) {
                int col = j * 16 + l15;
                if (col < NCLS && row < N_NODES)
                    H2b[(size_t)row * NCLS + col] = f2bf(acc[i][j][r]);
            }
        }
    }
}

// ---- agg2 v3: wave per node, inline softmax, bf16 H2 gather, writes d_out ----
__global__ __launch_bounds__(256) void agg2_csr_kernel(const int* __restrict__ row_ptr,
                                                       const int2* __restrict__ E2,
                                                       const float* __restrict__ AS,
                                                       const float* __restrict__ AD,
                                                       const unsigned short* __restrict__ H2b,
                                                       const float* __restrict__ b2,
                                                       float* __restrict__ OUT) {
    int lane = threadIdx.x & 63;
    int n = blockIdx.x * 4 + (threadIdx.x >> 6);
    if (n >= N_NODES) return;
    int beg = row_ptr[n];
    int end = (n + 1 < N_NODES) ? row_ptr[n + 1] : ET;
    float ad = AD[n];
    bool act = lane < NCLS;
    float den = 0.f, acc = 0.f;
    int p = beg;
    for (; p + 4 <= end; p += 4) {
        int2 e0 = E2[p], e1 = E2[p + 1], e2 = E2[p + 2], e3 = E2[p + 3];
        float pe0 = __expf(leaky(AS[e0.x] + ad));
        float pe1 = __expf(leaky(AS[e1.x] + ad));
        float pe2 = __expf(leaky(AS[e2.x] + ad));
        float pe3 = __expf(leaky(AS[e3.x] + ad));
        den += pe0 + pe1 + pe2 + pe3;
        if (act) {
            float h0 = bf2f(H2b[(size_t)e0.x * NCLS + lane]);
            float h1 = bf2f(H2b[(size_t)e1.x * NCLS + lane]);
            float h2 = bf2f(H2b[(size_t)e2.x * NCLS + lane]);
            float h3 = bf2f(H2b[(size_t)e3.x * NCLS + lane]);
            acc += pe0 * __int_as_float(e0.y) * h0 + pe1 * __int_as_float(e1.y) * h1
                 + pe2 * __int_as_float(e2.y) * h2 + pe3 * __int_as_float(e3.y) * h3;
        }
    }
    for (; p < end; p++) {
        int2 e0 = E2[p];
        float pe0 = __expf(leaky(AS[e0.x] + ad));
        den += pe0;
        if (act) acc += pe0 * __int_as_float(e0.y) * bf2f(H2b[(size_t)e0.x * NCLS + lane]);
    }
    if (act) {
        float r = 1.f / (den + 1e-16f);
        OUT[(size_t)n * NCLS + lane] = acc * r + b2[lane];
    }
}

extern "C" void kernel_launch(void* const* d_in, const int* in_sizes, int n_in,
                              void* d_out, int out_size, void* d_ws, size_t ws_size,
                              hipStream_t stream) {
    const float* x    = (const float*)d_in[0];
    const int*   ei   = (const int*)d_in[1];
    const float* ew   = (const float*)d_in[2];
    const float* W1   = (const float*)d_in[3];
    const float* a_s1 = (const float*)d_in[4];
    const float* a_d1 = (const float*)d_in[5];
    const float* b1   = (const float*)d_in[6];
    const float* W2   = (const float*)d_in[7];
    const float* a_s2 = (const float*)d_in[8];
    const float* a_d2 = (const float*)d_in[9];
    const float* b2   = (const float*)d_in[10];
    float* out = (float*)d_out;

    // workspace:
    //  H1b[N*256 bf16] | OUT1b[N*256 bf16] | AS1[N*4] | AD1[N*4]
    //  | row_ptr[N] | cnt[N] | fill[N] | E2[ET int2] | sums[NCHUNK] | WT[256*512 bf16]
    //  layer2 (H2b bf16 + AS2 + AD2, ~4.4 MB) aliases into H1b (25.6 MB, dead after agg1).
    unsigned short* H1b  = (unsigned short*)d_ws;
    unsigned short* OUT1b = H1b + (size_t)N_NODES * C1;
    float* AS1  = (float*)(OUT1b + (size_t)N_NODES * C1);
    float* AD1  = AS1 + N_NODES * HEADS;
    int* row_ptr = (int*)(AD1 + N_NODES * HEADS);
    int* cnt  = row_ptr + N_NODES;
    int* fill = cnt + N_NODES;
    int2* E2  = (int2*)(fill + N_NODES);
    int* sums = (int*)(E2 + ET);
    unsigned short* WT = (unsigned short*)(sums + NCHUNK);
    unsigned short* H2b = H1b;             // alias (H1b dead before gemm2 writes)
    float* AS2  = (float*)(H2b + (size_t)N_NODES * NCLS);
    float* AD2  = AS2 + N_NODES;

    // ---- CSR build + weight prep ----
    hipMemsetAsync(cnt, 0, N_NODES * sizeof(int), stream);
    wt_prep_kernel<<<dim3(F_IN / 32, C1 / 32), dim3(32, 8), 0, stream>>>(W1, WT);
    hist_kernel<<<(ET + 255) / 256, 256, 0, stream>>>(ei, cnt);
    chunk_sum_kernel<<<NCHUNK, 256, 0, stream>>>(cnt, sums);
    scan_sums_kernel<<<1, 256, 0, stream>>>(sums);
    rowptr_kernel<<<NCHUNK, 256, 0, stream>>>(cnt, sums, row_ptr, fill);
    scatter_kernel<<<(ET + 255) / 256, 256, 0, stream>>>(ei, ew, fill, E2);

    // ---- layer 1 ----
    gemm1_mfma_kernel<<<(N_NODES + 127) / 128, 512, 0, stream>>>(x, WT, H1b);
    alphas1_kernel<<<(N_NODES * HEADS + 255) / 256, 256, 0, stream>>>(H1b, a_s1, a_d1, AS1, AD1);
    agg1_csr_kernel<<<(N_NODES + 3) / 4, 256, 0, stream>>>(row_ptr, E2, AS1, AD1, H1b, b1, OUT1b);

    // ---- layer 2 ----
    gemm2_mfma_kernel<<<(N_NODES + 255) / 256, 512, 0, stream>>>(OUT1b, W2, a_s2, a_d2, H2b, AS2, AD2);
    agg2_csr_kernel<<<(N_NODES + 3) / 4, 256, 0, stream>>>(row_ptr, E2, AS2, AD2, H2b, b2, out);
}

// Round 8
// 425.545 us; speedup vs baseline: 8.7575x; 1.0276x over previous
//
#include <hip/hip_runtime.h>
#include <math.h>

#define N_NODES 50000
#define N_EDGES 800000
#define ET (N_EDGES + N_NODES)   /* 850000 edges incl. self-loops */
#define F_IN 512
#define HID 64
#define HEADS 4
#define C1 (HEADS * HID)         /* 256 */
#define NCLS 40
#define NEG_SLOPE 0.2f
#define NCHUNK ((N_NODES + 255) / 256)   /* 196 */

typedef __attribute__((ext_vector_type(8))) short short8;
typedef __attribute__((ext_vector_type(4))) float floatx4;

__device__ __forceinline__ float leaky(float x) { return x >= 0.f ? x : NEG_SLOPE * x; }

// f32 -> bf16 round-to-nearest-even
__device__ __forceinline__ unsigned short f2bf(float f) {
    unsigned u = __float_as_uint(f);
    u += 0x7fffu + ((u >> 16) & 1u);
    return (unsigned short)(u >> 16);
}
__device__ __forceinline__ float bf2f(unsigned short u) {
    return __uint_as_float(((unsigned)u) << 16);
}

__device__ __forceinline__ void edge_sd(int e, const int* __restrict__ ei,
                                        const float* __restrict__ ew,
                                        int& s, int& d, float& w) {
    if (e < N_EDGES) { s = ei[e]; d = ei[N_EDGES + e]; w = ew[e]; }
    else             { s = d = e - N_EDGES; w = 1.f; }
}

// ======================= CSR construction (per call) =======================
__global__ void hist_kernel(const int* __restrict__ ei, int* __restrict__ cnt) {
    int e = blockIdx.x * blockDim.x + threadIdx.x;
    if (e >= ET) return;
    int d = (e < N_EDGES) ? ei[N_EDGES + e] : e - N_EDGES;
    atomicAdd(&cnt[d], 1);
}

__global__ void chunk_sum_kernel(const int* __restrict__ cnt, int* __restrict__ sums) {
    __shared__ int sm[256];
    int i = blockIdx.x * 256 + threadIdx.x;
    sm[threadIdx.x] = (i < N_NODES) ? cnt[i] : 0;
    __syncthreads();
    for (int s = 128; s > 0; s >>= 1) {
        if (threadIdx.x < s) sm[threadIdx.x] += sm[threadIdx.x + s];
        __syncthreads();
    }
    if (threadIdx.x == 0) sums[blockIdx.x] = sm[0];
}

__global__ void scan_sums_kernel(int* __restrict__ sums) {
    __shared__ int sm[256];
    int i = threadIdx.x;
    int v = (i < NCHUNK) ? sums[i] : 0;
    sm[i] = v;
    __syncthreads();
    #pragma unroll
    for (int s = 1; s < 256; s <<= 1) {
        int t = (i >= s) ? sm[i - s] : 0;
        __syncthreads();
        sm[i] += t;
        __syncthreads();
    }
    if (i < NCHUNK) sums[i] = sm[i] - v;   // exclusive
}

__global__ void rowptr_kernel(const int* __restrict__ cnt, const int* __restrict__ sums,
                              int* __restrict__ row_ptr, int* __restrict__ fill) {
    __shared__ int sm[256];
    int i = blockIdx.x * 256 + threadIdx.x;
    int v = (i < N_NODES) ? cnt[i] : 0;
    sm[threadIdx.x] = v;
    __syncthreads();
    #pragma unroll
    for (int s = 1; s < 256; s <<= 1) {
        int t = (threadIdx.x >= s) ? sm[threadIdx.x - s] : 0;
        __syncthreads();
        sm[threadIdx.x] += t;
        __syncthreads();
    }
    int excl = sm[threadIdx.x] - v + sums[blockIdx.x];
    if (i < N_NODES) { row_ptr[i] = excl; fill[i] = excl; }
}

// CSR payload: (src, edge_weight) packed in one int2 per edge
__global__ void scatter_kernel(const int* __restrict__ ei, const float* __restrict__ ew,
                               int* __restrict__ fill, int2* __restrict__ E2) {
    int e = blockIdx.x * blockDim.x + threadIdx.x;
    if (e >= ET) return;
    int s, d; float w;
    edge_sd(e, ei, ew, s, d, w);
    int pos = atomicAdd(&fill[d], 1);
    E2[pos] = make_int2(s, __float_as_int(w));
}

// ============ W1 -> bf16 transpose: WT[n][k] = bf16(W1[k][n]) ============
__global__ void wt_prep_kernel(const float* __restrict__ W, unsigned short* __restrict__ WT) {
    __shared__ float tile[32][33];
    int k0 = blockIdx.x * 32;
    int n0 = blockIdx.y * 32;
    int tx = threadIdx.x, ty = threadIdx.y;    // 32 x 8
    #pragma unroll
    for (int i = 0; i < 32; i += 8)
        tile[ty + i][tx] = W[(size_t)(k0 + ty + i) * C1 + n0 + tx];
    __syncthreads();
    #pragma unroll
    for (int i = 0; i < 32; i += 8)
        WT[(size_t)(n0 + ty + i) * F_IN + k0 + tx] = f2bf(tile[tx][ty + i]);
}

// ====== GEMM1 (bf16 MFMA) + fused alphas1: X @ W1 -> H1 (bf16), AS1/AD1 ======
// Wave (wm,wn) owns cols wn*64..wn*64+63 == head wn exactly, so per-row logits
// for head wn reduce entirely within the wave (16-lane shuffle over l15).
__global__ __launch_bounds__(512) void gemm1_mfma_kernel(const float* __restrict__ X,
                                                         const unsigned short* __restrict__ WT,
                                                         const float* __restrict__ a_s1,
                                                         const float* __restrict__ a_d1,
                                                         unsigned short* __restrict__ H,
                                                         float* __restrict__ AS,
                                                         float* __restrict__ AD) {
    __shared__ short As[128][40];
    __shared__ short Bs[256][40];
    const int t = threadIdx.x;
    const int m0 = blockIdx.x * 128;
    const int lane = t & 63;
    const int wave = t >> 6;
    const int wm = wave >> 2;
    const int wn = wave & 3;
    const int l15 = lane & 15;
    const int quad = lane >> 4;

    const int ar = t >> 2;
    const int ac0 = (t & 3) * 8;
    const int gr = m0 + ar;
    const int bn = t >> 1;
    const int bc0 = (t & 1) * 16;

    floatx4 acc[4][4];
    #pragma unroll
    for (int i = 0; i < 4; i++)
        #pragma unroll
        for (int j = 0; j < 4; j++) acc[i][j] = (floatx4){0.f, 0.f, 0.f, 0.f};

    for (int k0 = 0; k0 < F_IN; k0 += 32) {
        float xv[8];
        if (gr < N_NODES) {
            const float4* p = (const float4*)(X + (size_t)gr * F_IN + k0 + ac0);
            float4 v0 = p[0], v1 = p[1];
            xv[0] = v0.x; xv[1] = v0.y; xv[2] = v0.z; xv[3] = v0.w;
            xv[4] = v1.x; xv[5] = v1.y; xv[6] = v1.z; xv[7] = v1.w;
        } else {
            #pragma unroll
            for (int i = 0; i < 8; i++) xv[i] = 0.f;
        }
        short8 av;
        #pragma unroll
        for (int i = 0; i < 8; i++) av[i] = (short)f2bf(xv[i]);
        *(short8*)&As[ar][ac0] = av;

        const short8* q = (const short8*)(WT + (size_t)bn * F_IN + k0 + bc0);
        *(short8*)&Bs[bn][bc0]     = q[0];
        *(short8*)&Bs[bn][bc0 + 8] = q[1];
        __syncthreads();

        short8 a[4], b[4];
        #pragma unroll
        for (int i = 0; i < 4; i++)
            a[i] = *(const short8*)&As[wm * 64 + i * 16 + l15][quad * 8];
        #pragma unroll
        for (int j = 0; j < 4; j++)
            b[j] = *(const short8*)&Bs[wn * 64 + j * 16 + l15][quad * 8];
        #pragma unroll
        for (int i = 0; i < 4; i++)
            #pragma unroll
            for (int j = 0; j < 4; j++)
                acc[i][j] = __builtin_amdgcn_mfma_f32_16x16x32_bf16(a[i], b[j], acc[i][j], 0, 0, 0);
        __syncthreads();
    }

    // attention-vector slices for head wn (layout [HEADS][HID], HID=64)
    float asr[4], adr[4];
    #pragma unroll
    for (int j = 0; j < 4; j++) {
        asr[j] = a_s1[wn * HID + j * 16 + l15];
        adr[j] = a_d1[wn * HID + j * 16 + l15];
    }

    #pragma unroll
    for (int i = 0; i < 4; i++) {
        int rbase = m0 + wm * 64 + i * 16 + quad * 4;
        #pragma unroll
        for (int j = 0; j < 4; j++) {
            int col = wn * 64 + j * 16 + l15;
            #pragma unroll
            for (int r = 0; r < 4; r++) {
                int row = rbase + r;
                if (row < N_NODES) H[(size_t)row * C1 + col] = f2bf(acc[i][j][r]);
            }
        }
        // fused logits: reduce over l15 (16 lanes), rows stay within quad group
        #pragma unroll
        for (int r = 0; r < 4; r++) {
            int row = rbase + r;
            float s_ = acc[i][0][r] * asr[0] + acc[i][1][r] * asr[1]
                     + acc[i][2][r] * asr[2] + acc[i][3][r] * asr[3];
            float d_ = acc[i][0][r] * adr[0] + acc[i][1][r] * adr[1]
                     + acc[i][2][r] * adr[2] + acc[i][3][r] * adr[3];
            #pragma unroll
            for (int m = 8; m; m >>= 1) { s_ += __shfl_xor(s_, m); d_ += __shfl_xor(d_, m); }
            if (l15 == 0 && row < N_NODES) {
                AS[row * 4 + wn] = s_;
                AD[row * 4 + wn] = d_;
            }
        }
    }
}

// ---- agg1 v4: wave per node, 4 ch/thread, 4-edge unroll, lane-specialized
//      softmax: lane j=lane&3 computes exp for edge p+j only (per its head),
//      shares (src, pe*w) via ds_bpermute butterfly (LDS pipe, not VALU).
//      Per-lane den partials butterfly-reduced before the remainder loop. ----
__global__ __launch_bounds__(256) void agg1_csr_kernel(const int* __restrict__ row_ptr,
                                                       const int2* __restrict__ E2,
                                                       const float* __restrict__ AS,
                                                       const float* __restrict__ AD,
                                                       const unsigned short* __restrict__ H,
                                                       const float* __restrict__ b1,
                                                       unsigned short* __restrict__ OUT) {
    int n = blockIdx.x * 4 + (threadIdx.x >> 6);
    int lane = threadIdx.x & 63;
    if (n >= N_NODES) return;
    int c0 = lane * 4;                  // 4 channels per thread
    int h = lane >> 4;                  // head
    int j = lane & 3;                   // edge slot within 4-group
    int beg = row_ptr[n];
    int end = (n + 1 < N_NODES) ? row_ptr[n + 1] : ET;
    float ad = AD[n * 4 + h];
    float den = 0.f;
    float a0 = 0.f, a1 = 0.f, a2 = 0.f, a3 = 0.f;
    int p = beg;
    for (; p + 4 <= end; p += 4) {
        int2 e = E2[p + j];
        float pe = __expf(leaky(AS[e.x * 4 + h] + ad));
        den += pe;
        float pw = pe * __int_as_float(e.y);
        int s0 = e.x;
        // butterfly share: after this every lane holds all 4 (s,pw) of the group
        int   s1 = __shfl_xor(s0, 1);
        float pw1 = __shfl_xor(pw, 1);
        int   s2 = __shfl_xor(s0, 2);
        float pw2 = __shfl_xor(pw, 2);
        int   s3 = __shfl_xor(s1, 2);
        float pw3 = __shfl_xor(pw1, 2);
        uint2 u0 = *(const uint2*)(H + (size_t)s0 * C1 + c0);
        uint2 u1 = *(const uint2*)(H + (size_t)s1 * C1 + c0);
        uint2 u2 = *(const uint2*)(H + (size_t)s2 * C1 + c0);
        uint2 u3 = *(const uint2*)(H + (size_t)s3 * C1 + c0);
        a0 += pw  * __uint_as_float(u0.x << 16)         + pw1 * __uint_as_float(u1.x << 16)
            + pw2 * __uint_as_float(u2.x << 16)         + pw3 * __uint_as_float(u3.x << 16);
        a1 += pw  * __uint_as_float(u0.x & 0xffff0000u) + pw1 * __uint_as_float(u1.x & 0xffff0000u)
            + pw2 * __uint_as_float(u2.x & 0xffff0000u) + pw3 * __uint_as_float(u3.x & 0xffff0000u);
        a2 += pw  * __uint_as_float(u0.y << 16)         + pw1 * __uint_as_float(u1.y << 16)
            + pw2 * __uint_as_float(u2.y << 16)         + pw3 * __uint_as_float(u3.y << 16);
        a3 += pw  * __uint_as_float(u0.y & 0xffff0000u) + pw1 * __uint_as_float(u1.y & 0xffff0000u)
            + pw2 * __uint_as_float(u2.y & 0xffff0000u) + pw3 * __uint_as_float(u3.y & 0xffff0000u);
    }
    // combine den partials across the 4 edge slots (same head group)
    den += __shfl_xor(den, 1);
    den += __shfl_xor(den, 2);
    // remainder: all lanes process each edge directly (no sharing)
    for (; p < end; p++) {
        int2 e0 = E2[p];
        float pe0 = __expf(leaky(AS[e0.x * 4 + h] + ad));
        den += pe0;
        float pw0 = pe0 * __int_as_float(e0.y);
        uint2 u0 = *(const uint2*)(H + (size_t)e0.x * C1 + c0);
        a0 += pw0 * __uint_as_float(u0.x << 16);
        a1 += pw0 * __uint_as_float(u0.x & 0xffff0000u);
        a2 += pw0 * __uint_as_float(u0.y << 16);
        a3 += pw0 * __uint_as_float(u0.y & 0xffff0000u);
    }
    float r = 1.f / (den + 1e-16f);
    float4 bv = *(const float4*)(b1 + c0);
    float v0 = a0 * r + bv.x, v1 = a1 * r + bv.y, v2 = a2 * r + bv.z, v3 = a3 * r + bv.w;
    v0 = v0 > 0.f ? v0 : 0.f;
    v1 = v1 > 0.f ? v1 : 0.f;
    v2 = v2 > 0.f ? v2 : 0.f;
    v3 = v3 > 0.f ? v3 : 0.f;
    uint2 o;
    o.x = ((unsigned)f2bf(v1) << 16) | (unsigned)f2bf(v0);
    o.y = ((unsigned)f2bf(v3) << 16) | (unsigned)f2bf(v2);
    *(uint2*)(OUT + (size_t)n * C1 + c0) = o;
}

// ====== GEMM2 (bf16 MFMA) + fused alphas2: OUT1b @ W2 -> H2b (bf16), AS2/AD2 ======
#define BROW 264   /* LDS row stride for Bs2: 528B, 16B-aligned */
__global__ __launch_bounds__(512) void gemm2_mfma_kernel(const unsigned short* __restrict__ A,
                                                         const float* __restrict__ W2,
                                                         const float* __restrict__ a_s2,
                                                         const float* __restrict__ a_d2,
                                                         unsigned short* __restrict__ H2b,
                                                         float* __restrict__ AS2,
                                                         float* __restrict__ AD2) {
    __shared__ short As[256][40];        // 20 KB
    __shared__ short Bs[48 * BROW];      // 25.3 KB
    const int t = threadIdx.x;
    const int m0 = blockIdx.x * 256;
    const int lane = t & 63;
    const int wave = t >> 6;
    const int l15 = lane & 15;
    const int quad = lane >> 4;

    for (int i = t; i < 48 * 256; i += 512) {
        int n = i >> 8, k = i & 255;
        float v = (n < NCLS) ? W2[k * NCLS + n] : 0.f;
        Bs[n * BROW + k] = (short)f2bf(v);
    }

    const int ar = t >> 1;
    const int ac0 = (t & 1) * 16;

    floatx4 acc[2][3];
    #pragma unroll
    for (int i = 0; i < 2; i++)
        #pragma unroll
        for (int j = 0; j < 3; j++) acc[i][j] = (floatx4){0.f, 0.f, 0.f, 0.f};

    for (int k0 = 0; k0 < C1; k0 += 32) {
        const short8* q = (const short8*)(A + (size_t)(m0 + ar) * C1 + k0 + ac0);
        short8 v0 = q[0], v1 = q[1];
        __syncthreads();
        *(short8*)&As[ar][ac0]     = v0;
        *(short8*)&As[ar][ac0 + 8] = v1;
        __syncthreads();

        short8 a[2], b[3];
        #pragma unroll
        for (int i = 0; i < 2; i++)
            a[i] = *(const short8*)&As[wave * 32 + i * 16 + l15][quad * 8];
        #pragma unroll
        for (int j = 0; j < 3; j++)
            b[j] = *(const short8*)&Bs[(j * 16 + l15) * BROW + k0 + quad * 8];
        #pragma unroll
        for (int i = 0; i < 2; i++)
            #pragma unroll
            for (int j = 0; j < 3; j++)
                acc[i][j] = __builtin_amdgcn_mfma_f32_16x16x32_bf16(a[i], b[j], acc[i][j], 0, 0, 0);
    }

    float asr[3], adr[3];
    #pragma unroll
    for (int j = 0; j < 3; j++) {
        int col = j * 16 + l15;
        asr[j] = (col < NCLS) ? a_s2[col] : 0.f;
        adr[j] = (col < NCLS) ? a_d2[col] : 0.f;
    }

    #pragma unroll
    for (int i = 0; i < 2; i++) {
        #pragma unroll
        for (int r = 0; r < 4; r++) {
            int row = m0 + wave * 32 + i * 16 + quad * 4 + r;
            float s_ = acc[i][0][r] * asr[0] + acc[i][1][r] * asr[1] + acc[i][2][r] * asr[2];
            float d_ = acc[i][0][r] * adr[0] + acc[i][1][r] * adr[1] + acc[i][2][r] * adr[2];
            #pragma unroll
            for (int m = 8; m; m >>= 1) { s_ += __shfl_xor(s_, m); d_ += __shfl_xor(d_, m); }
            if (l15 == 0 && row < N_NODES) { AS2[row] = s_; AD2[row] = d_; }
            #pragma unroll
            for (int j = 0; j < 3; j++) {
                int col = j * 16 + l15;
                if (col < NCLS && row < N_NODES)
                    H2b[(size_t)row * NCLS + col] = f2bf(acc[i][j][r]);
            }
        }
    }
}

// ---- agg2 v4: wave per node, lane-specialized softmax, bf16 H2 gather ----
__global__ __launch_bounds__(256) void agg2_csr_kernel(const int* __restrict__ row_ptr,
                                                       const int2* __restrict__ E2,
                                                       const float* __restrict__ AS,
                                                       const float* __restrict__ AD,
                                                       const unsigned short* __restrict__ H2b,
                                                       const float* __restrict__ b2,
                                                       float* __restrict__ OUT) {
    int lane = threadIdx.x & 63;
    int n = blockIdx.x * 4 + (threadIdx.x >> 6);
    if (n >= N_NODES) return;
    int j = lane & 3;
    int beg = row_ptr[n];
    int end = (n + 1 < N_NODES) ? row_ptr[n + 1] : ET;
    float ad = AD[n];
    bool act = lane < NCLS;
    float den = 0.f, acc = 0.f;
    int p = beg;
    for (; p + 4 <= end; p += 4) {
        int2 e = E2[p + j];
        float pe = __expf(leaky(AS[e.x] + ad));
        den += pe;
        float pw = pe * __int_as_float(e.y);
        int s0 = e.x;
        int   s1 = __shfl_xor(s0, 1);
        float pw1 = __shfl_xor(pw, 1);
        int   s2 = __shfl_xor(s0, 2);
        float pw2 = __shfl_xor(pw, 2);
        int   s3 = __shfl_xor(s1, 2);
        float pw3 = __shfl_xor(pw1, 2);
        if (act) {
            float h0 = bf2f(H2b[(size_t)s0 * NCLS + lane]);
            float h1 = bf2f(H2b[(size_t)s1 * NCLS + lane]);
            float h2 = bf2f(H2b[(size_t)s2 * NCLS + lane]);
            float h3 = bf2f(H2b[(size_t)s3 * NCLS + lane]);
            acc += pw * h0 + pw1 * h1 + pw2 * h2 + pw3 * h3;
        }
    }
    den += __shfl_xor(den, 1);
    den += __shfl_xor(den, 2);
    for (; p < end; p++) {
        int2 e0 = E2[p];
        float pe0 = __expf(leaky(AS[e0.x] + ad));
        den += pe0;
        if (act) acc += pe0 * __int_as_float(e0.y) * bf2f(H2b[(size_t)e0.x * NCLS + lane]);
    }
    if (act) {
        float r = 1.f / (den + 1e-16f);
        OUT[(size_t)n * NCLS + lane] = acc * r + b2[lane];
    }
}

extern "C" void kernel_launch(void* const* d_in, const int* in_sizes, int n_in,
                              void* d_out, int out_size, void* d_ws, size_t ws_size,
                              hipStream_t stream) {
    const float* x    = (const float*)d_in[0];
    const int*   ei   = (const int*)d_in[1];
    const float* ew   = (const float*)d_in[2];
    const float* W1   = (const float*)d_in[3];
    const float* a_s1 = (const float*)d_in[4];
    const float* a_d1 = (const float*)d_in[5];
    const float* b1   = (const float*)d_in[6];
    const float* W2   = (const float*)d_in[7];
    const float* a_s2 = (const float*)d_in[8];
    const float* a_d2 = (const float*)d_in[9];
    const float* b2   = (const float*)d_in[10];
    float* out = (float*)d_out;

    unsigned short* H1b  = (unsigned short*)d_ws;
    unsigned short* OUT1b = H1b + (size_t)N_NODES * C1;
    float* AS1  = (float*)(OUT1b + (size_t)N_NODES * C1);
    float* AD1  = AS1 + N_NODES * HEADS;
    int* row_ptr = (int*)(AD1 + N_NODES * HEADS);
    int* cnt  = row_ptr + N_NODES;
    int* fill = cnt + N_NODES;
    int2* E2  = (int2*)(fill + N_NODES);
    int* sums = (int*)(E2 + ET);
    unsigned short* WT = (unsigned short*)(sums + NCHUNK);
    unsigned short* H2b = H1b;             // alias (H1b dead before gemm2 writes)
    float* AS2  = (float*)(H2b + (size_t)N_NODES * NCLS);
    float* AD2  = AS2 + N_NODES;

    // ---- CSR build + weight prep ----
    hipMemsetAsync(cnt, 0, N_NODES * sizeof(int), stream);
    wt_prep_kernel<<<dim3(F_IN / 32, C1 / 32), dim3(32, 8), 0, stream>>>(W1, WT);
    hist_kernel<<<(ET + 255) / 256, 256, 0, stream>>>(ei, cnt);
    chunk_sum_kernel<<<NCHUNK, 256, 0, stream>>>(cnt, sums);
    scan_sums_kernel<<<1, 256, 0, stream>>>(sums);
    rowptr_kernel<<<NCHUNK, 256, 0, stream>>>(cnt, sums, row_ptr, fill);
    scatter_kernel<<<(ET + 255) / 256, 256, 0, stream>>>(ei, ew, fill, E2);

    // ---- layer 1 ----
    gemm1_mfma_kernel<<<(N_NODES + 127) / 128, 512, 0, stream>>>(x, WT, a_s1, a_d1, H1b, AS1, AD1);
    agg1_csr_kernel<<<(N_NODES + 3) / 4, 256, 0, stream>>>(row_ptr, E2, AS1, AD1, H1b, b1, OUT1b);

    // ---- layer 2 ----
    gemm2_mfma_kernel<<<(N_NODES + 255) / 256, 512, 0, stream>>>(OUT1b, W2, a_s2, a_d2, H2b, AS2, AD2);
    agg2_csr_kernel<<<(N_NODES + 3) / 4, 256, 0, stream>>>(row_ptr, E2, AS2, AD2, H2b, b2, out);
}

// Round 9
// 396.663 us; speedup vs baseline: 9.3951x; 1.0728x over previous
//
#include <hip/hip_runtime.h>
#include <math.h>

#define N_NODES 50000
#define N_EDGES 800000
#define ET (N_EDGES + N_NODES)   /* 850000 edges incl. self-loops */
#define F_IN 512
#define HID 64
#define HEADS 4
#define C1 (HEADS * HID)         /* 256 */
#define NCLS 40
#define NEG_SLOPE 0.2f
#define NCHUNK ((N_NODES + 255) / 256)   /* 196 */

typedef __attribute__((ext_vector_type(8))) short short8;
typedef __attribute__((ext_vector_type(4))) float floatx4;

__device__ __forceinline__ float leaky(float x) { return fmaxf(x, NEG_SLOPE * x); }

// f32 -> bf16 round-to-nearest-even
__device__ __forceinline__ unsigned short f2bf(float f) {
    unsigned u = __float_as_uint(f);
    u += 0x7fffu + ((u >> 16) & 1u);
    return (unsigned short)(u >> 16);
}
__device__ __forceinline__ float bf2f(unsigned short u) {
    return __uint_as_float(((unsigned)u) << 16);
}

__device__ __forceinline__ void edge_sd(int e, const int* __restrict__ ei,
                                        const float* __restrict__ ew,
                                        int& s, int& d, float& w) {
    if (e < N_EDGES) { s = ei[e]; d = ei[N_EDGES + e]; w = ew[e]; }
    else             { s = d = e - N_EDGES; w = 1.f; }
}

// ======================= CSR construction (per call) =======================
__global__ void hist_kernel(const int* __restrict__ ei, int* __restrict__ cnt) {
    int e = blockIdx.x * blockDim.x + threadIdx.x;
    if (e >= ET) return;
    int d = (e < N_EDGES) ? ei[N_EDGES + e] : e - N_EDGES;
    atomicAdd(&cnt[d], 1);
}

__global__ void chunk_sum_kernel(const int* __restrict__ cnt, int* __restrict__ sums) {
    __shared__ int sm[256];
    int i = blockIdx.x * 256 + threadIdx.x;
    sm[threadIdx.x] = (i < N_NODES) ? cnt[i] : 0;
    __syncthreads();
    for (int s = 128; s > 0; s >>= 1) {
        if (threadIdx.x < s) sm[threadIdx.x] += sm[threadIdx.x + s];
        __syncthreads();
    }
    if (threadIdx.x == 0) sums[blockIdx.x] = sm[0];
}

__global__ void scan_sums_kernel(int* __restrict__ sums) {
    __shared__ int sm[256];
    int i = threadIdx.x;
    int v = (i < NCHUNK) ? sums[i] : 0;
    sm[i] = v;
    __syncthreads();
    #pragma unroll
    for (int s = 1; s < 256; s <<= 1) {
        int t = (i >= s) ? sm[i - s] : 0;
        __syncthreads();
        sm[i] += t;
        __syncthreads();
    }
    if (i < NCHUNK) sums[i] = sm[i] - v;   // exclusive
}

__global__ void rowptr_kernel(const int* __restrict__ cnt, const int* __restrict__ sums,
                              int* __restrict__ row_ptr, int* __restrict__ fill) {
    __shared__ int sm[256];
    int i = blockIdx.x * 256 + threadIdx.x;
    int v = (i < N_NODES) ? cnt[i] : 0;
    sm[threadIdx.x] = v;
    __syncthreads();
    #pragma unroll
    for (int s = 1; s < 256; s <<= 1) {
        int t = (threadIdx.x >= s) ? sm[threadIdx.x - s] : 0;
        __syncthreads();
        sm[threadIdx.x] += t;
        __syncthreads();
    }
    int excl = sm[threadIdx.x] - v + sums[blockIdx.x];
    if (i < N_NODES) { row_ptr[i] = excl; fill[i] = excl; }
}

// CSR payload: (src, edge_weight) packed in one int2 per edge
__global__ void scatter_kernel(const int* __restrict__ ei, const float* __restrict__ ew,
                               int* __restrict__ fill, int2* __restrict__ E2) {
    int e = blockIdx.x * blockDim.x + threadIdx.x;
    if (e >= ET) return;
    int s, d; float w;
    edge_sd(e, ei, ew, s, d, w);
    int pos = atomicAdd(&fill[d], 1);
    E2[pos] = make_int2(s, __float_as_int(w));
}

// ============ W1 -> bf16 transpose: WT[n][k] = bf16(W1[k][n]) ============
__global__ void wt_prep_kernel(const float* __restrict__ W, unsigned short* __restrict__ WT) {
    __shared__ float tile[32][33];
    int k0 = blockIdx.x * 32;
    int n0 = blockIdx.y * 32;
    int tx = threadIdx.x, ty = threadIdx.y;    // 32 x 8
    #pragma unroll
    for (int i = 0; i < 32; i += 8)
        tile[ty + i][tx] = W[(size_t)(k0 + ty + i) * C1 + n0 + tx];
    __syncthreads();
    #pragma unroll
    for (int i = 0; i < 32; i += 8)
        WT[(size_t)(n0 + ty + i) * F_IN + k0 + tx] = f2bf(tile[tx][ty + i]);
}

// ====== GEMM1 (bf16 MFMA) + fused alphas1: X @ W1 -> H1 (bf16), AS1/AD1 ======
__global__ __launch_bounds__(512) void gemm1_mfma_kernel(const float* __restrict__ X,
                                                         const unsigned short* __restrict__ WT,
                                                         const float* __restrict__ a_s1,
                                                         const float* __restrict__ a_d1,
                                                         unsigned short* __restrict__ H,
                                                         float* __restrict__ AS,
                                                         float* __restrict__ AD) {
    __shared__ short As[128][40];
    __shared__ short Bs[256][40];
    const int t = threadIdx.x;
    const int m0 = blockIdx.x * 128;
    const int lane = t & 63;
    const int wave = t >> 6;
    const int wm = wave >> 2;
    const int wn = wave & 3;
    const int l15 = lane & 15;
    const int quad = lane >> 4;

    const int ar = t >> 2;
    const int ac0 = (t & 3) * 8;
    const int gr = m0 + ar;
    const int bn = t >> 1;
    const int bc0 = (t & 1) * 16;

    floatx4 acc[4][4];
    #pragma unroll
    for (int i = 0; i < 4; i++)
        #pragma unroll
        for (int j = 0; j < 4; j++) acc[i][j] = (floatx4){0.f, 0.f, 0.f, 0.f};

    for (int k0 = 0; k0 < F_IN; k0 += 32) {
        float xv[8];
        if (gr < N_NODES) {
            const float4* p = (const float4*)(X + (size_t)gr * F_IN + k0 + ac0);
            float4 v0 = p[0], v1 = p[1];
            xv[0] = v0.x; xv[1] = v0.y; xv[2] = v0.z; xv[3] = v0.w;
            xv[4] = v1.x; xv[5] = v1.y; xv[6] = v1.z; xv[7] = v1.w;
        } else {
            #pragma unroll
            for (int i = 0; i < 8; i++) xv[i] = 0.f;
        }
        short8 av;
        #pragma unroll
        for (int i = 0; i < 8; i++) av[i] = (short)f2bf(xv[i]);
        *(short8*)&As[ar][ac0] = av;

        const short8* q = (const short8*)(WT + (size_t)bn * F_IN + k0 + bc0);
        *(short8*)&Bs[bn][bc0]     = q[0];
        *(short8*)&Bs[bn][bc0 + 8] = q[1];
        __syncthreads();

        short8 a[4], b[4];
        #pragma unroll
        for (int i = 0; i < 4; i++)
            a[i] = *(const short8*)&As[wm * 64 + i * 16 + l15][quad * 8];
        #pragma unroll
        for (int j = 0; j < 4; j++)
            b[j] = *(const short8*)&Bs[wn * 64 + j * 16 + l15][quad * 8];
        #pragma unroll
        for (int i = 0; i < 4; i++)
            #pragma unroll
            for (int j = 0; j < 4; j++)
                acc[i][j] = __builtin_amdgcn_mfma_f32_16x16x32_bf16(a[i], b[j], acc[i][j], 0, 0, 0);
        __syncthreads();
    }

    float asr[4], adr[4];
    #pragma unroll
    for (int j = 0; j < 4; j++) {
        asr[j] = a_s1[wn * HID + j * 16 + l15];
        adr[j] = a_d1[wn * HID + j * 16 + l15];
    }

    #pragma unroll
    for (int i = 0; i < 4; i++) {
        int rbase = m0 + wm * 64 + i * 16 + quad * 4;
        #pragma unroll
        for (int j = 0; j < 4; j++) {
            int col = wn * 64 + j * 16 + l15;
            #pragma unroll
            for (int r = 0; r < 4; r++) {
                int row = rbase + r;
                if (row < N_NODES) H[(size_t)row * C1 + col] = f2bf(acc[i][j][r]);
            }
        }
        #pragma unroll
        for (int r = 0; r < 4; r++) {
            int row = rbase + r;
            float s_ = acc[i][0][r] * asr[0] + acc[i][1][r] * asr[1]
                     + acc[i][2][r] * asr[2] + acc[i][3][r] * asr[3];
            float d_ = acc[i][0][r] * adr[0] + acc[i][1][r] * adr[1]
                     + acc[i][2][r] * adr[2] + acc[i][3][r] * adr[3];
            #pragma unroll
            for (int m = 8; m; m >>= 1) { s_ += __shfl_xor(s_, m); d_ += __shfl_xor(d_, m); }
            if (l15 == 0 && row < N_NODES) {
                AS[row * 4 + wn] = s_;
                AD[row * 4 + wn] = d_;
            }
        }
    }
}

// ---- agg1 v5: wave per node, 16-edge chunks, two-phase.
//      Phase 1: lane (l15,h) computes pe for edge base+l15 head h -> one exp
//      per (edge,head), zero redundancy. Phase 2: src via __shfl(s,p) with
//      WAVE-UNIFORM p (-> v_readlane, scalar pipe; gather addresses never
//      wait on LDS pipe); pw via per-lane __shfl (needed only at FMA time,
//      overlaps gather latency). Den partials butterfly-reduced at end. ----
__global__ __launch_bounds__(256) void agg1_csr_kernel(const int* __restrict__ row_ptr,
                                                       const int2* __restrict__ E2,
                                                       const float* __restrict__ AS,
                                                       const float* __restrict__ AD,
                                                       const unsigned short* __restrict__ H,
                                                       const float* __restrict__ b1,
                                                       unsigned short* __restrict__ OUT) {
    int n = blockIdx.x * 4 + (threadIdx.x >> 6);
    int lane = threadIdx.x & 63;
    if (n >= N_NODES) return;
    int l15 = lane & 15;
    int h = lane >> 4;
    int c0 = lane * 4;
    int beg = row_ptr[n];
    int end = (n + 1 < N_NODES) ? row_ptr[n + 1] : ET;
    float ad = AD[n * 4 + h];
    float den = 0.f;
    float a0 = 0.f, a1 = 0.f, a2 = 0.f, a3 = 0.f;

    for (int base = beg; base < end; base += 16) {
        int m = end - base; if (m > 16) m = 16;
        // phase 1: one exp per (edge, head)
        float pw = 0.f; int s = 0;
        if (l15 < m) {
            int2 e = E2[base + l15];
            s = e.x;
            float pe = __expf(leaky(AS[e.x * 4 + h] + ad));
            den += pe;
            pw = pe * __int_as_float(e.y);
        }
        // phase 2: gather + FMA
        int p = 0;
        for (; p + 4 <= m; p += 4) {
            int s0 = __shfl(s, p);
            int s1 = __shfl(s, p + 1);
            int s2 = __shfl(s, p + 2);
            int s3 = __shfl(s, p + 3);
            uint2 u0 = *(const uint2*)(H + (size_t)s0 * C1 + c0);
            uint2 u1 = *(const uint2*)(H + (size_t)s1 * C1 + c0);
            uint2 u2 = *(const uint2*)(H + (size_t)s2 * C1 + c0);
            uint2 u3 = *(const uint2*)(H + (size_t)s3 * C1 + c0);
            float w0 = __shfl(pw, h * 16 + p);
            float w1 = __shfl(pw, h * 16 + p + 1);
            float w2 = __shfl(pw, h * 16 + p + 2);
            float w3 = __shfl(pw, h * 16 + p + 3);
            a0 += w0 * __uint_as_float(u0.x << 16)         + w1 * __uint_as_float(u1.x << 16)
                + w2 * __uint_as_float(u2.x << 16)         + w3 * __uint_as_float(u3.x << 16);
            a1 += w0 * __uint_as_float(u0.x & 0xffff0000u) + w1 * __uint_as_float(u1.x & 0xffff0000u)
                + w2 * __uint_as_float(u2.x & 0xffff0000u) + w3 * __uint_as_float(u3.x & 0xffff0000u);
            a2 += w0 * __uint_as_float(u0.y << 16)         + w1 * __uint_as_float(u1.y << 16)
                + w2 * __uint_as_float(u2.y << 16)         + w3 * __uint_as_float(u3.y << 16);
            a3 += w0 * __uint_as_float(u0.y & 0xffff0000u) + w1 * __uint_as_float(u1.y & 0xffff0000u)
                + w2 * __uint_as_float(u2.y & 0xffff0000u) + w3 * __uint_as_float(u3.y & 0xffff0000u);
        }
        for (; p < m; p++) {
            int s0 = __shfl(s, p);
            uint2 u0 = *(const uint2*)(H + (size_t)s0 * C1 + c0);
            float w0 = __shfl(pw, h * 16 + p);
            a0 += w0 * __uint_as_float(u0.x << 16);
            a1 += w0 * __uint_as_float(u0.x & 0xffff0000u);
            a2 += w0 * __uint_as_float(u0.y << 16);
            a3 += w0 * __uint_as_float(u0.y & 0xffff0000u);
        }
    }
    // reduce den over the 16 lanes of this head group
    den += __shfl_xor(den, 1);
    den += __shfl_xor(den, 2);
    den += __shfl_xor(den, 4);
    den += __shfl_xor(den, 8);

    float r = 1.f / (den + 1e-16f);
    float4 bv = *(const float4*)(b1 + c0);
    float v0 = a0 * r + bv.x, v1 = a1 * r + bv.y, v2 = a2 * r + bv.z, v3 = a3 * r + bv.w;
    v0 = v0 > 0.f ? v0 : 0.f;
    v1 = v1 > 0.f ? v1 : 0.f;
    v2 = v2 > 0.f ? v2 : 0.f;
    v3 = v3 > 0.f ? v3 : 0.f;
    uint2 o;
    o.x = ((unsigned)f2bf(v1) << 16) | (unsigned)f2bf(v0);
    o.y = ((unsigned)f2bf(v3) << 16) | (unsigned)f2bf(v2);
    *(uint2*)(OUT + (size_t)n * C1 + c0) = o;
}

// ====== GEMM2 (bf16 MFMA) + fused alphas2: OUT1b @ W2 -> H2b (bf16), AS2/AD2 ======
#define BROW 264   /* LDS row stride for Bs2: 528B, 16B-aligned */
__global__ __launch_bounds__(512) void gemm2_mfma_kernel(const unsigned short* __restrict__ A,
                                                         const float* __restrict__ W2,
                                                         const float* __restrict__ a_s2,
                                                         const float* __restrict__ a_d2,
                                                         unsigned short* __restrict__ H2b,
                                                         float* __restrict__ AS2,
                                                         float* __restrict__ AD2) {
    __shared__ short As[256][40];        // 20 KB
    __shared__ short Bs[48 * BROW];      // 25.3 KB
    const int t = threadIdx.x;
    const int m0 = blockIdx.x * 256;
    const int lane = t & 63;
    const int wave = t >> 6;
    const int l15 = lane & 15;
    const int quad = lane >> 4;

    for (int i = t; i < 48 * 256; i += 512) {
        int n = i >> 8, k = i & 255;
        float v = (n < NCLS) ? W2[k * NCLS + n] : 0.f;
        Bs[n * BROW + k] = (short)f2bf(v);
    }

    const int ar = t >> 1;
    const int ac0 = (t & 1) * 16;

    floatx4 acc[2][3];
    #pragma unroll
    for (int i = 0; i < 2; i++)
        #pragma unroll
        for (int j = 0; j < 3; j++) acc[i][j] = (floatx4){0.f, 0.f, 0.f, 0.f};

    for (int k0 = 0; k0 < C1; k0 += 32) {
        const short8* q = (const short8*)(A + (size_t)(m0 + ar) * C1 + k0 + ac0);
        short8 v0 = q[0], v1 = q[1];
        __syncthreads();
        *(short8*)&As[ar][ac0]     = v0;
        *(short8*)&As[ar][ac0 + 8] = v1;
        __syncthreads();

        short8 a[2], b[3];
        #pragma unroll
        for (int i = 0; i < 2; i++)
            a[i] = *(const short8*)&As[wave * 32 + i * 16 + l15][quad * 8];
        #pragma unroll
        for (int j = 0; j < 3; j++)
            b[j] = *(const short8*)&Bs[(j * 16 + l15) * BROW + k0 + quad * 8];
        #pragma unroll
        for (int i = 0; i < 2; i++)
            #pragma unroll
            for (int j = 0; j < 3; j++)
                acc[i][j] = __builtin_amdgcn_mfma_f32_16x16x32_bf16(a[i], b[j], acc[i][j], 0, 0, 0);
    }

    float asr[3], adr[3];
    #pragma unroll
    for (int j = 0; j < 3; j++) {
        int col = j * 16 + l15;
        asr[j] = (col < NCLS) ? a_s2[col] : 0.f;
        adr[j] = (col < NCLS) ? a_d2[col] : 0.f;
    }

    #pragma unroll
    for (int i = 0; i < 2; i++) {
        #pragma unroll
        for (int r = 0; r < 4; r++) {
            int row = m0 + wave * 32 + i * 16 + quad * 4 + r;
            float s_ = acc[i][0][r] * asr[0] + acc[i][1][r] * asr[1] + acc[i][2][r] * asr[2];
            float d_ = acc[i][0][r] * adr[0] + acc[i][1][r] * adr[1] + acc[i][2][r] * adr[2];
            #pragma unroll
            for (int m = 8; m; m >>= 1) { s_ += __shfl_xor(s_, m); d_ += __shfl_xor(d_, m); }
            if (l15 == 0 && row < N_NODES) { AS2[row] = s_; AD2[row] = d_; }
            #pragma unroll
            for (int j = 0; j < 3; j++) {
                int col = j * 16 + l15;
                if (col < NCLS && row < N_NODES)
                    H2b[(size_t)row * NCLS + col] = f2bf(acc[i][j][r]);
            }
        }
    }
}

// ---- agg2 v5: wave per node, 64-edge chunks, two-phase; single head so both
//      s and pw broadcasts are wave-uniform readlanes. ----
__global__ __launch_bounds__(256) void agg2_csr_kernel(const int* __restrict__ row_ptr,
                                                       const int2* __restrict__ E2,
                                                       const float* __restrict__ AS,
                                                       const float* __restrict__ AD,
                                                       const unsigned short* __restrict__ H2b,
                                                       const float* __restrict__ b2,
                                                       float* __restrict__ OUT) {
    int lane = threadIdx.x & 63;
    int n = blockIdx.x * 4 + (threadIdx.x >> 6);
    if (n >= N_NODES) return;
    int beg = row_ptr[n];
    int end = (n + 1 < N_NODES) ? row_ptr[n + 1] : ET;
    float ad = AD[n];
    bool act = lane < NCLS;
    float den = 0.f, acc = 0.f;

    for (int base = beg; base < end; base += 64) {
        int m = end - base; if (m > 64) m = 64;
        float pw = 0.f; int s = 0;
        if (lane < m) {
            int2 e = E2[base + lane];
            s = e.x;
            float pe = __expf(leaky(AS[e.x] + ad));
            den += pe;
            pw = pe * __int_as_float(e.y);
        }
        int p = 0;
        for (; p + 4 <= m; p += 4) {
            int s0 = __shfl(s, p);
            int s1 = __shfl(s, p + 1);
            int s2 = __shfl(s, p + 2);
            int s3 = __shfl(s, p + 3);
            float w0 = __shfl(pw, p);
            float w1 = __shfl(pw, p + 1);
            float w2 = __shfl(pw, p + 2);
            float w3 = __shfl(pw, p + 3);
            if (act) {
                float h0 = bf2f(H2b[(size_t)s0 * NCLS + lane]);
                float h1 = bf2f(H2b[(size_t)s1 * NCLS + lane]);
                float h2 = bf2f(H2b[(size_t)s2 * NCLS + lane]);
                float h3 = bf2f(H2b[(size_t)s3 * NCLS + lane]);
                acc += w0 * h0 + w1 * h1 + w2 * h2 + w3 * h3;
            }
        }
        for (; p < m; p++) {
            int s0 = __shfl(s, p);
            float w0 = __shfl(pw, p);
            if (act) acc += w0 * bf2f(H2b[(size_t)s0 * NCLS + lane]);
        }
    }
    den += __shfl_xor(den, 1);
    den += __shfl_xor(den, 2);
    den += __shfl_xor(den, 4);
    den += __shfl_xor(den, 8);
    den += __shfl_xor(den, 16);
    den += __shfl_xor(den, 32);
    if (act) {
        float r = 1.f / (den + 1e-16f);
        OUT[(size_t)n * NCLS + lane] = acc * r + b2[lane];
    }
}

extern "C" void kernel_launch(void* const* d_in, const int* in_sizes, int n_in,
                              void* d_out, int out_size, void* d_ws, size_t ws_size,
                              hipStream_t stream) {
    const float* x    = (const float*)d_in[0];
    const int*   ei   = (const int*)d_in[1];
    const float* ew   = (const float*)d_in[2];
    const float* W1   = (const float*)d_in[3];
    const float* a_s1 = (const float*)d_in[4];
    const float* a_d1 = (const float*)d_in[5];
    const float* b1   = (const float*)d_in[6];
    const float* W2   = (const float*)d_in[7];
    const float* a_s2 = (const float*)d_in[8];
    const float* a_d2 = (const float*)d_in[9];
    const float* b2   = (const float*)d_in[10];
    float* out = (float*)d_out;

    unsigned short* H1b  = (unsigned short*)d_ws;
    unsigned short* OUT1b = H1b + (size_t)N_NODES * C1;
    float* AS1  = (float*)(OUT1b + (size_t)N_NODES * C1);
    float* AD1  = AS1 + N_NODES * HEADS;
    int* row_ptr = (int*)(AD1 + N_NODES * HEADS);
    int* cnt  = row_ptr + N_NODES;
    int* fill = cnt + N_NODES;
    int2* E2  = (int2*)(fill + N_NODES);
    int* sums = (int*)(E2 + ET);
    unsigned short* WT = (unsigned short*)(sums + NCHUNK);
    unsigned short* H2b = H1b;             // alias (H1b dead before gemm2 writes)
    float* AS2  = (float*)(H2b + (size_t)N_NODES * NCLS);
    float* AD2  = AS2 + N_NODES;

    // ---- CSR build + weight prep ----
    hipMemsetAsync(cnt, 0, N_NODES * sizeof(int), stream);
    wt_prep_kernel<<<dim3(F_IN / 32, C1 / 32), dim3(32, 8), 0, stream>>>(W1, WT);
    hist_kernel<<<(ET + 255) / 256, 256, 0, stream>>>(ei, cnt);
    chunk_sum_kernel<<<NCHUNK, 256, 0, stream>>>(cnt, sums);
    scan_sums_kernel<<<1, 256, 0, stream>>>(sums);
    rowptr_kernel<<<NCHUNK, 256, 0, stream>>>(cnt, sums, row_ptr, fill);
    scatter_kernel<<<(ET + 255) / 256, 256, 0, stream>>>(ei, ew, fill, E2);

    // ---- layer 1 ----
    gemm1_mfma_kernel<<<(N_NODES + 127) / 128, 512, 0, stream>>>(x, WT, a_s1, a_d1, H1b, AS1, AD1);
    agg1_csr_kernel<<<(N_NODES + 3) / 4, 256, 0, stream>>>(row_ptr, E2, AS1, AD1, H1b, b1, OUT1b);

    // ---- layer 2 ----
    gemm2_mfma_kernel<<<(N_NODES + 255) / 256, 512, 0, stream>>>(OUT1b, W2, a_s2, a_d2, H2b, AS2, AD2);
    agg2_csr_kernel<<<(N_NODES + 3) / 4, 256, 0, stream>>>(row_ptr, E2, AS2, AD2, H2b, b2, out);
}